// Round 4
// baseline (2240.188 us; speedup 1.0000x reference)
//
#include <hip/hip_runtime.h>

// Problem constants (fixed by the reference)
static constexpr int HD   = 128;   // hidden
static constexpr int D1   = 256;
static constexpr int D2   = 128;
static constexpr int NCLS = 10;
static constexpr int NG   = 64;    // graphs/segments

// ---------------- CSR build ----------------

__global__ void count_edges_k(const int* __restrict__ row, int E, int* __restrict__ cnt) {
    int e = blockIdx.x * 256 + threadIdx.x;
    if (e < E) atomicAdd(&cnt[row[e]], 1);
}

__global__ void scan_partial_k(const int* __restrict__ cnt, int N, int* __restrict__ partial) {
    __shared__ int s[256];
    int base = blockIdx.x * 1024;
    int sum = 0;
    for (int i = threadIdx.x; i < 1024; i += 256) {
        int idx = base + i;
        if (idx < N) sum += cnt[idx];
    }
    s[threadIdx.x] = sum;
    __syncthreads();
    for (int st = 128; st > 0; st >>= 1) {
        if (threadIdx.x < st) s[threadIdx.x] += s[threadIdx.x + st];
        __syncthreads();
    }
    if (threadIdx.x == 0) partial[blockIdx.x] = s[0];
}

__global__ void scan_partials_serial_k(int* partial, int nb) {
    if (threadIdx.x == 0 && blockIdx.x == 0) {
        int acc = 0;
        for (int i = 0; i < nb; i++) { int v = partial[i]; partial[i] = acc; acc += v; }
    }
}

__global__ void scan_final_k(const int* __restrict__ cnt, int N, const int* __restrict__ partial,
                             int* __restrict__ row_start) {
    __shared__ int s[2][1024];
    int t = threadIdx.x;
    int idx = blockIdx.x * 1024 + t;
    int v = (idx < N) ? cnt[idx] : 0;
    s[0][t] = v;
    __syncthreads();
    int cur = 0;
    for (int st = 1; st < 1024; st <<= 1) {
        int val = s[cur][t];
        if (t >= st) val += s[cur][t - st];
        s[cur ^ 1][t] = val;
        __syncthreads();
        cur ^= 1;
    }
    if (idx < N) row_start[idx] = partial[blockIdx.x] + s[cur][t] - v;  // exclusive
}

__global__ void fill_csr_k(const int* __restrict__ row, const int* __restrict__ col, int E,
                           const int* __restrict__ row_start, int* __restrict__ cursor,
                           int* __restrict__ csr) {
    int e = blockIdx.x * 256 + threadIdx.x;
    if (e < E) {
        int r = row[e];
        int p = atomicAdd(&cursor[r], 1);
        csr[row_start[r] + p] = col[e];
    }
}

// ---------------- mean aggregation (wave per row) ----------------

// FIN=50 path: scalar loads (50 floats doesn't tile into 64 lanes cleanly)
__global__ __launch_bounds__(256) void aggregate50_k(const float* __restrict__ x,
                                                     const int* __restrict__ row_start,
                                                     const int* __restrict__ cnt,
                                                     const int* __restrict__ csr, int N,
                                                     float* __restrict__ agg) {
    int wave = threadIdx.x >> 6;
    int lane = threadIdx.x & 63;
    int i = blockIdx.x * 4 + wave;
    if (i >= N) return;
    int start = row_start[i];
    int deg = cnt[i];
    float acc = 0.f;
    for (int base = 0; base < deg; base += 64) {
        int nch = min(64, deg - base);
        int c = (base + lane < deg) ? csr[start + base + lane] : 0;
        for (int j = 0; j < nch; j++) {
            int cj = __shfl(c, j, 64);
            if (lane < 50) acc += x[(size_t)cj * 50 + lane];
        }
    }
    float inv = 1.f / fmaxf((float)deg, 1.f);
    if (lane < 50) agg[(size_t)i * 50 + lane] = acc * inv;
}

// FIN=128 path: one float2 per lane = exactly one 512B row per wave-load
__global__ __launch_bounds__(256) void aggregate128_k(const float* __restrict__ x,
                                                      const int* __restrict__ row_start,
                                                      const int* __restrict__ cnt,
                                                      const int* __restrict__ csr, int N,
                                                      float* __restrict__ agg) {
    int wave = threadIdx.x >> 6;
    int lane = threadIdx.x & 63;
    int i = blockIdx.x * 4 + wave;
    if (i >= N) return;
    int start = row_start[i];
    int deg = cnt[i];
    float ax = 0.f, ay = 0.f;
    for (int base = 0; base < deg; base += 64) {
        int nch = min(64, deg - base);
        int c = (base + lane < deg) ? csr[start + base + lane] : 0;
        for (int j = 0; j < nch; j++) {
            int cj = __shfl(c, j, 64);
            const float2 v = *reinterpret_cast<const float2*>(&x[(size_t)cj * 128 + 2 * lane]);
            ax += v.x;
            ay += v.y;
        }
    }
    float inv = 1.f / fmaxf((float)deg, 1.f);
    float2 o;
    o.x = ax * inv;
    o.y = ay * inv;
    *reinterpret_cast<float2*>(&agg[(size_t)i * 128 + 2 * lane]) = o;
}

// ---------------- fused concat-GEMM: hout[N,128] = [xin|agg] @ W + b ----------------

template <int FIN>
__global__ __launch_bounds__(256) void gemm_concat_k(const float* __restrict__ xin,
                                                     const float* __restrict__ agg,
                                                     const float* __restrict__ W,
                                                     const float* __restrict__ bias, int N,
                                                     float* __restrict__ hout) {
    constexpr int K = 2 * FIN;
    __shared__ float Ws[32][128];
    __shared__ float Xs[32][32];
    int tid = threadIdx.x;
    int tx = tid & 63;        // col pair: tx, tx+64
    int ty = tid >> 6;        // 0..3 -> rows ty*8 .. ty*8+7
    int rowBase = blockIdx.x * 32;
    float acc0[8], acc1[8];
#pragma unroll
    for (int r = 0; r < 8; r++) { acc0[r] = 0.f; acc1[r] = 0.f; }

    for (int k0 = 0; k0 < K; k0 += 32) {
        // stage X tile [32 rows][32 k]
#pragma unroll
        for (int l = 0; l < 4; l++) {
            int idx = tid + l * 256;
            int rr = idx >> 5, kk = idx & 31;
            int gr = rowBase + rr;
            int k = k0 + kk;
            float v = 0.f;
            if (gr < N && k < K)
                v = (k < FIN) ? xin[(size_t)gr * FIN + k] : agg[(size_t)gr * FIN + (k - FIN)];
            Xs[rr][kk] = v;
        }
        // stage W tile [32 k][128 cols]
#pragma unroll
        for (int l = 0; l < 16; l++) {
            int idx = tid + l * 256;
            int kk = idx >> 7, j = idx & 127;
            int k = k0 + kk;
            Ws[kk][j] = (k < K) ? W[(size_t)k * 128 + j] : 0.f;
        }
        __syncthreads();
#pragma unroll
        for (int kg = 0; kg < 8; kg++) {
            float w0[4], w1[4];
#pragma unroll
            for (int u = 0; u < 4; u++) {
                w0[u] = Ws[kg * 4 + u][tx];
                w1[u] = Ws[kg * 4 + u][tx + 64];
            }
#pragma unroll
            for (int r = 0; r < 8; r++) {
                const float4 xv = *reinterpret_cast<const float4*>(&Xs[ty * 8 + r][kg * 4]);
                acc0[r] += xv.x * w0[0] + xv.y * w0[1] + xv.z * w0[2] + xv.w * w0[3];
                acc1[r] += xv.x * w1[0] + xv.y * w1[1] + xv.z * w1[2] + xv.w * w1[3];
            }
        }
        __syncthreads();
    }
    float bv0 = bias[tx], bv1 = bias[tx + 64];
#pragma unroll
    for (int r = 0; r < 8; r++) {
        int gr = rowBase + ty * 8 + r;
        if (gr < N) {
            hout[(size_t)gr * 128 + tx] = acc0[r] + bv0;
            hout[(size_t)gr * 128 + tx + 64] = acc1[r] + bv1;
        }
    }
}

// ---------------- epilogue: l2-normalize row -> relu -> inference BN ----------------

__global__ __launch_bounds__(256) void l2_relu_bn_k(float* __restrict__ h, int N,
                                                    const float* __restrict__ gamma,
                                                    const float* __restrict__ beta,
                                                    const float* __restrict__ mean,
                                                    const float* __restrict__ var) {
    int wave = threadIdx.x >> 6, lane = threadIdx.x & 63;
    int i = blockIdx.x * 4 + wave;
    if (i >= N) return;
    float v0 = h[(size_t)i * 128 + lane];
    float v1 = h[(size_t)i * 128 + 64 + lane];
    float ss = v0 * v0 + v1 * v1;
#pragma unroll
    for (int o = 32; o > 0; o >>= 1) ss += __shfl_xor(ss, o, 64);
    float rs = rsqrtf(fmaxf(ss, 1e-12f));
    v0 = fmaxf(v0 * rs, 0.f);
    v1 = fmaxf(v1 * rs, 0.f);
    v0 = (v0 - mean[lane]) * rsqrtf(var[lane] + 1e-3f) * gamma[lane] + beta[lane];
    v1 = (v1 - mean[lane + 64]) * rsqrtf(var[lane + 64] + 1e-3f) * gamma[lane + 64] + beta[lane + 64];
    h[(size_t)i * 128 + lane] = v0;
    h[(size_t)i * 128 + 64 + lane] = v1;
}

// ---------------- segment (graph) pooling ----------------

__global__ void segcnt_k(const int* __restrict__ seg, int N, int* __restrict__ scnt) {
    int i = blockIdx.x * 256 + threadIdx.x;
    if (i < N) atomicAdd(&scnt[seg[i]], 1);
}

__global__ __launch_bounds__(128) void pool_k(const float* __restrict__ h,
                                              const int* __restrict__ seg, int N,
                                              float* __restrict__ pool) {
    int tx = threadIdx.x;  // feature 0..127
    int r0 = blockIdx.x * 256;
    int rend = min(r0 + 256, N);
    if (r0 >= N) return;
    int cur = seg[r0];
    float sum = 0.f;
    for (int r = r0; r < rend; r++) {
        int s = seg[r];
        float v = h[(size_t)r * 128 + tx];
        if (s != cur) {
            atomicAdd(&pool[cur * 128 + tx], sum);
            cur = s;
            sum = v;
        } else {
            sum += v;
        }
    }
    atomicAdd(&pool[cur * 128 + tx], sum);
}

// ---------------- dense head: 64 blocks, one graph each ----------------

__global__ __launch_bounds__(256) void head_k(const float* __restrict__ pool,
                                              const int* __restrict__ scnt,
                                              const float* __restrict__ dw1, const float* __restrict__ db1,
                                              const float* __restrict__ dw2, const float* __restrict__ db2,
                                              const float* __restrict__ dw3, const float* __restrict__ db3,
                                              float* __restrict__ out) {
    __shared__ float p[128];
    __shared__ float z1[256];
    __shared__ float z2[128];
    __shared__ float z3[16];
    int g = blockIdx.x;
    int t = threadIdx.x;
    if (t < 128) {
        float c = fmaxf((float)scnt[g], 1.f);
        p[t] = pool[g * 128 + t] / c;
    }
    __syncthreads();
    {
        float acc = db1[t];
        for (int k = 0; k < 128; k++) acc += p[k] * dw1[k * D1 + t];
        z1[t] = fmaxf(acc, 0.f);
    }
    __syncthreads();
    if (t < 128) {
        float acc = db2[t];
        for (int k = 0; k < 256; k++) acc += z1[k] * dw2[k * D2 + t];
        z2[t] = fmaxf(acc, 0.f);
    }
    __syncthreads();
    if (t < NCLS) {
        float acc = db3[t];
        for (int k = 0; k < 128; k++) acc += z2[k] * dw3[k * NCLS + t];
        z3[t] = acc;
    }
    __syncthreads();
    if (t == 0) {
        float mx = -1e30f;
        for (int j = 0; j < NCLS; j++) mx = fmaxf(mx, z3[j]);
        float sum = 0.f;
        float e[NCLS];
        for (int j = 0; j < NCLS; j++) { e[j] = expf(z3[j] - mx); sum += e[j]; }
        for (int j = 0; j < NCLS; j++) out[g * NCLS + j] = e[j] / sum;
    }
}

// ---------------- launch ----------------

extern "C" void kernel_launch(void* const* d_in, const int* in_sizes, int n_in,
                              void* d_out, int out_size, void* d_ws, size_t ws_size,
                              hipStream_t stream) {
    const float* x    = (const float*)d_in[0];
    const int* erow   = (const int*)d_in[1];
    const int* ecol   = (const int*)d_in[2];
    const int* seg    = (const int*)d_in[3];
    const float* w1   = (const float*)d_in[4];
    const float* b1   = (const float*)d_in[5];
    const float* w2   = (const float*)d_in[6];
    const float* b2   = (const float*)d_in[7];
    const float* w3   = (const float*)d_in[8];
    const float* b3   = (const float*)d_in[9];
    const float* g1   = (const float*)d_in[10];
    const float* be1  = (const float*)d_in[11];
    const float* m1   = (const float*)d_in[12];
    const float* v1   = (const float*)d_in[13];
    const float* g2   = (const float*)d_in[14];
    const float* be2  = (const float*)d_in[15];
    const float* m2   = (const float*)d_in[16];
    const float* v2   = (const float*)d_in[17];
    const float* g3   = (const float*)d_in[18];
    const float* be3  = (const float*)d_in[19];
    const float* m3   = (const float*)d_in[20];
    const float* v3   = (const float*)d_in[21];
    const float* dw1  = (const float*)d_in[22];
    const float* db1  = (const float*)d_in[23];
    const float* dw2  = (const float*)d_in[24];
    const float* db2  = (const float*)d_in[25];
    const float* dw3  = (const float*)d_in[26];
    const float* db3  = (const float*)d_in[27];
    float* out = (float*)d_out;

    const int N = in_sizes[3];
    const int E = in_sizes[1];

    char* ws = (char*)d_ws;
    size_t off = 0;
    auto alloc = [&](size_t bytes) -> char* {
        off = (off + 255) & ~(size_t)255;
        char* p = ws + off;
        off += bytes;
        return p;
    };
    int* cnt       = (int*)alloc((size_t)N * 4);
    int* cursor    = (int*)alloc((size_t)N * 4);
    int* row_start = (int*)alloc((size_t)N * 4);
    int* partial   = (int*)alloc(1024 * 4);
    int* csr       = (int*)alloc((size_t)E * 4);
    float* agg     = (float*)alloc((size_t)N * 128 * 4);
    float* ha      = (float*)alloc((size_t)N * 128 * 4);
    float* hb      = (float*)alloc((size_t)N * 128 * 4);
    float* pool    = (float*)alloc((size_t)NG * 128 * 4);
    int* scnt      = (int*)alloc((size_t)NG * 4);

    hipMemsetAsync(cnt, 0, (size_t)N * 4, stream);
    hipMemsetAsync(cursor, 0, (size_t)N * 4, stream);
    hipMemsetAsync(pool, 0, (size_t)NG * 128 * 4, stream);
    hipMemsetAsync(scnt, 0, (size_t)NG * 4, stream);

    const int nbScan = (N + 1023) / 1024;
    count_edges_k<<<(E + 255) / 256, 256, 0, stream>>>(erow, E, cnt);
    scan_partial_k<<<nbScan, 256, 0, stream>>>(cnt, N, partial);
    scan_partials_serial_k<<<1, 64, 0, stream>>>(partial, nbScan);
    scan_final_k<<<nbScan, 1024, 0, stream>>>(cnt, N, partial, row_start);
    fill_csr_k<<<(E + 255) / 256, 256, 0, stream>>>(erow, ecol, E, row_start, cursor, csr);

    const int aggGrid = (N + 3) / 4;
    const int gemmGrid = (N + 31) / 32;

    // layer 1 (Fin=50, K=100)
    aggregate50_k<<<aggGrid, 256, 0, stream>>>(x, row_start, cnt, csr, N, agg);
    gemm_concat_k<50><<<gemmGrid, 256, 0, stream>>>(x, agg, w1, b1, N, ha);
    l2_relu_bn_k<<<aggGrid, 256, 0, stream>>>(ha, N, g1, be1, m1, v1);
    // layer 2 (Fin=128, K=256)
    aggregate128_k<<<aggGrid, 256, 0, stream>>>(ha, row_start, cnt, csr, N, agg);
    gemm_concat_k<128><<<gemmGrid, 256, 0, stream>>>(ha, agg, w2, b2, N, hb);
    l2_relu_bn_k<<<aggGrid, 256, 0, stream>>>(hb, N, g2, be2, m2, v2);
    // layer 3 (Fin=128, K=256)
    aggregate128_k<<<aggGrid, 256, 0, stream>>>(hb, row_start, cnt, csr, N, agg);
    gemm_concat_k<128><<<gemmGrid, 256, 0, stream>>>(hb, agg, w3, b3, N, ha);
    l2_relu_bn_k<<<aggGrid, 256, 0, stream>>>(ha, N, g3, be3, m3, v3);

    // pooling + head
    segcnt_k<<<(N + 255) / 256, 256, 0, stream>>>(seg, N, scnt);
    pool_k<<<(N + 255) / 256, 128, 0, stream>>>(ha, seg, N, pool);
    head_k<<<NG, 256, 0, stream>>>(pool, scnt, dw1, db1, dw2, db2, dw3, db3, out);
}

// Round 5
// 1452.749 us; speedup vs baseline: 1.5420x; 1.5420x over previous
//
#include <hip/hip_runtime.h>

static constexpr int D1   = 256;
static constexpr int D2   = 128;
static constexpr int NCLS = 10;
static constexpr int NG   = 64;

// ---------------- CSR build ----------------

__global__ void count_edges_k(const int* __restrict__ row, int E, int* __restrict__ cnt) {
    int e = blockIdx.x * 256 + threadIdx.x;
    if (e < E) atomicAdd(&cnt[row[e]], 1);
}

__global__ void scan_partial_k(const int* __restrict__ cnt, int N, int* __restrict__ partial) {
    __shared__ int s[256];
    int base = blockIdx.x * 1024;
    int sum = 0;
    for (int i = threadIdx.x; i < 1024; i += 256) {
        int idx = base + i;
        if (idx < N) sum += cnt[idx];
    }
    s[threadIdx.x] = sum;
    __syncthreads();
    for (int st = 128; st > 0; st >>= 1) {
        if (threadIdx.x < st) s[threadIdx.x] += s[threadIdx.x + st];
        __syncthreads();
    }
    if (threadIdx.x == 0) partial[blockIdx.x] = s[0];
}

__global__ void scan_partials_serial_k(int* partial, int nb) {
    if (threadIdx.x == 0 && blockIdx.x == 0) {
        int acc = 0;
        for (int i = 0; i < nb; i++) { int v = partial[i]; partial[i] = acc; acc += v; }
    }
}

__global__ void scan_final_k(const int* __restrict__ cnt, int N, const int* __restrict__ partial,
                             int* __restrict__ row_start) {
    __shared__ int s[2][1024];
    int t = threadIdx.x;
    int idx = blockIdx.x * 1024 + t;
    int v = (idx < N) ? cnt[idx] : 0;
    s[0][t] = v;
    __syncthreads();
    int cur = 0;
    for (int st = 1; st < 1024; st <<= 1) {
        int val = s[cur][t];
        if (t >= st) val += s[cur][t - st];
        s[cur ^ 1][t] = val;
        __syncthreads();
        cur ^= 1;
    }
    if (idx < N) row_start[idx] = partial[blockIdx.x] + s[cur][t] - v;  // exclusive
}

__global__ void fill_csr_k(const int* __restrict__ row, const int* __restrict__ col, int E,
                           const int* __restrict__ row_start, int* __restrict__ cursor,
                           int* __restrict__ csr) {
    int e = blockIdx.x * 256 + threadIdx.x;
    if (e < E) {
        int r = row[e];
        int p = atomicAdd(&cursor[r], 1);
        csr[row_start[r] + p] = col[e];
    }
}

// ---------------- pad kernels for layer-1 unification ----------------

// xp[N][128] = [x(50) | 0(14) | (agg written by aggregate50) | 0]
__global__ void copyx_k(const float* __restrict__ x, float* __restrict__ xp, int N) {
    int idx = blockIdx.x * 256 + threadIdx.x;  // N*64 threads
    int i = idx >> 6, lane = idx & 63;
    if (i < N) xp[(size_t)i * 128 + lane] = (lane < 50) ? x[(size_t)i * 50 + lane] : 0.f;
}

// wp[128][128]: rows 0-49 = w1 rows 0-49 (x part), rows 64-113 = w1 rows 50-99 (agg part), else 0
__global__ void w1pad_k(const float* __restrict__ w1, float* __restrict__ wp) {
    int idx = blockIdx.x * 256 + threadIdx.x;  // 128*128
    int k = idx >> 7, j = idx & 127;
    float v = 0.f;
    if (k < 50) v = w1[k * 128 + j];
    else if (k >= 64 && k < 114) v = w1[(k - 14) * 128 + j];
    wp[idx] = v;
}

// ---------------- mean aggregation (wave per row) ----------------

// FIN=50: writes into padded X layout (stride 128, offset 64), zeroing lanes 50..63
__global__ __launch_bounds__(256) void aggregate50_k(const float* __restrict__ x,
                                                     const int* __restrict__ row_start,
                                                     const int* __restrict__ cnt,
                                                     const int* __restrict__ csr, int N,
                                                     float* __restrict__ xp) {
    int wave = threadIdx.x >> 6;
    int lane = threadIdx.x & 63;
    int i = blockIdx.x * 4 + wave;
    if (i >= N) return;
    int start = row_start[i];
    int deg = cnt[i];
    float acc = 0.f;
    for (int base = 0; base < deg; base += 64) {
        int nch = min(64, deg - base);
        int c = (base + lane < deg) ? csr[start + base + lane] : 0;
        for (int j = 0; j < nch; j++) {
            int cj = __shfl(c, j, 64);
            if (lane < 50) acc += x[(size_t)cj * 50 + lane];
        }
    }
    float inv = 1.f / fmaxf((float)deg, 1.f);
    xp[(size_t)i * 128 + 64 + lane] = (lane < 50) ? acc * inv : 0.f;
}

// FIN=128: one float2 per lane = exactly one 512B row per wave-load
__global__ __launch_bounds__(256) void aggregate128_k(const float* __restrict__ x,
                                                      const int* __restrict__ row_start,
                                                      const int* __restrict__ cnt,
                                                      const int* __restrict__ csr, int N,
                                                      float* __restrict__ agg) {
    int wave = threadIdx.x >> 6;
    int lane = threadIdx.x & 63;
    int i = blockIdx.x * 4 + wave;
    if (i >= N) return;
    int start = row_start[i];
    int deg = cnt[i];
    float ax = 0.f, ay = 0.f;
    for (int base = 0; base < deg; base += 64) {
        int nch = min(64, deg - base);
        int c = (base + lane < deg) ? csr[start + base + lane] : 0;
        for (int j = 0; j < nch; j++) {
            int cj = __shfl(c, j, 64);
            const float2 v = *reinterpret_cast<const float2*>(&x[(size_t)cj * 128 + 2 * lane]);
            ax += v.x;
            ay += v.y;
        }
    }
    float inv = 1.f / fmaxf((float)deg, 1.f);
    float2 o;
    o.x = ax * inv;
    o.y = ay * inv;
    *reinterpret_cast<float2*>(&agg[(size_t)i * 128 + 2 * lane]) = o;
}

// ---------------- fused GEMM + l2norm + relu + BN ----------------
// out[N,128] = bn(relu(l2norm([A|B] @ W + bias)))
// A,B: halves of the concat input, both row-stride 128 floats. W: [K][128].
// Tile: 64 rows x 128 cols, K-step 32, double-buffered LDS via global_load_lds.

template <int KT>  // K = KT*32, FIN (half width) = KT*16; KT=4 (L1) or 8 (L2/3)
__global__ __launch_bounds__(256) void gemm_fused_k(
    const float* __restrict__ A, const float* __restrict__ B,
    const float* __restrict__ W, const float* __restrict__ bias,
    const float* __restrict__ gamma, const float* __restrict__ beta,
    const float* __restrict__ mean, const float* __restrict__ var,
    int N, float* __restrict__ out) {
    constexpr int K = KT * 32;
    constexpr int FIN = KT * 16;
    __shared__ float Xs[2][64 * 32];
    __shared__ float Ws[2][32 * 128];
    const int tid = threadIdx.x;
    const int lane = tid & 63;
    const int w = tid >> 6;
    const int rowBase = blockIdx.x * 64;

    float acc0[16], acc1[16];
#pragma unroll
    for (int r = 0; r < 16; r++) { acc0[r] = 0.f; acc1[r] = 0.f; }

    // issue one 64x32 X-tile + 32x128 W-tile into LDS buffer `buf` for k-offset k0.
    // LDS dst is wave-uniform base; HW scatters lane*16B (linear). Global src per-lane.
    auto issue = [&](int buf, int k0) {
#pragma unroll
        for (int c = 0; c < 2; ++c) {
            int m = w * 2 + c;                    // chunk 0..7
            int flat = m * 256 + lane * 4;        // float index in tile
            int rr = flat >> 5;
            int kk = flat & 31;
            int row = rowBase + rr;
            if (row > N - 1) row = N - 1;         // clamp: safe, result unused
            const float* g = (k0 < FIN) ? (A + (size_t)row * 128 + k0 + kk)
                                        : (B + (size_t)row * 128 + (k0 - FIN) + kk);
            __builtin_amdgcn_global_load_lds(
                (const __attribute__((address_space(1))) void*)g,
                (__attribute__((address_space(3))) void*)&Xs[buf][m * 256], 16, 0, 0);
        }
#pragma unroll
        for (int c = 0; c < 4; ++c) {
            int m = w * 4 + c;                    // chunk 0..15
            int flat = m * 256 + lane * 4;
            int kk = flat >> 7;
            int j = flat & 127;
            const float* g = W + (size_t)(k0 + kk) * 128 + j;
            __builtin_amdgcn_global_load_lds(
                (const __attribute__((address_space(1))) void*)g,
                (__attribute__((address_space(3))) void*)&Ws[buf][m * 256], 16, 0, 0);
        }
    };

    issue(0, 0);
    for (int t = 0; t < KT; ++t) {
        __syncthreads();  // compiler drains vmcnt before s_barrier -> buf[t&1] complete
        if (t + 1 < KT) issue((t + 1) & 1, (t + 1) * 32);
        const float* Xb = &Xs[t & 1][0];
        const float* Wb = &Ws[t & 1][0];
#pragma unroll
        for (int kg = 0; kg < 8; ++kg) {
            float w0[4], w1v[4];
#pragma unroll
            for (int u = 0; u < 4; ++u) {
                w0[u]  = Wb[(kg * 4 + u) * 128 + lane];        // conflict-free (2/bank)
                w1v[u] = Wb[(kg * 4 + u) * 128 + lane + 64];
            }
#pragma unroll
            for (int r = 0; r < 16; ++r) {
                const float4 xv = *reinterpret_cast<const float4*>(&Xb[(w * 16 + r) * 32 + kg * 4]);  // broadcast
                acc0[r] += xv.x * w0[0] + xv.y * w0[1] + xv.z * w0[2] + xv.w * w0[3];
                acc1[r] += xv.x * w1v[0] + xv.y * w1v[1] + xv.z * w1v[2] + xv.w * w1v[3];
            }
        }
    }

    // fused epilogue: +bias -> l2norm(row) -> relu -> BN. Row's 128 cols live in this wave.
    float mu0 = mean[lane], mu1 = mean[lane + 64];
    float sc0 = rsqrtf(var[lane] + 1e-3f) * gamma[lane];
    float sc1 = rsqrtf(var[lane + 64] + 1e-3f) * gamma[lane + 64];
    float bt0 = beta[lane], bt1 = beta[lane + 64];
    float bv0 = bias[lane], bv1 = bias[lane + 64];
#pragma unroll
    for (int r = 0; r < 16; ++r) {
        int gr = rowBase + w * 16 + r;
        float a0 = acc0[r] + bv0, a1 = acc1[r] + bv1;
        float ss = a0 * a0 + a1 * a1;
#pragma unroll
        for (int o = 32; o > 0; o >>= 1) ss += __shfl_xor(ss, o, 64);
        float rs = rsqrtf(fmaxf(ss, 1e-12f));
        a0 = fmaxf(a0 * rs, 0.f);
        a1 = fmaxf(a1 * rs, 0.f);
        a0 = (a0 - mu0) * sc0 + bt0;
        a1 = (a1 - mu1) * sc1 + bt1;
        if (gr < N) {
            out[(size_t)gr * 128 + lane] = a0;
            out[(size_t)gr * 128 + lane + 64] = a1;
        }
    }
}

// ---------------- segment (graph) pooling ----------------

__global__ __launch_bounds__(128) void pool_k(const float* __restrict__ h,
                                              const int* __restrict__ seg, int N,
                                              float* __restrict__ pool) {
    int tx = threadIdx.x;  // feature 0..127
    int r0 = blockIdx.x * 64;
    int rend = min(r0 + 64, N);
    if (r0 >= N) return;
    int cur = seg[r0];
    float sum = 0.f;
    for (int r = r0; r < rend; r++) {
        int s = seg[r];
        float v = h[(size_t)r * 128 + tx];
        if (s != cur) {
            atomicAdd(&pool[cur * 128 + tx], sum);
            cur = s;
            sum = v;
        } else {
            sum += v;
        }
    }
    atomicAdd(&pool[cur * 128 + tx], sum);
}

// ---------------- dense head: 64 blocks, one graph each ----------------
// seg counts via binary search on sorted seg (replaces the contended segcnt_k).

__global__ __launch_bounds__(256) void head_k(const float* __restrict__ pool,
                                              const int* __restrict__ seg, int N,
                                              const float* __restrict__ dw1, const float* __restrict__ db1,
                                              const float* __restrict__ dw2, const float* __restrict__ db2,
                                              const float* __restrict__ dw3, const float* __restrict__ db3,
                                              float* __restrict__ out) {
    __shared__ float p[128];
    __shared__ float z1[256];
    __shared__ float z2[128];
    __shared__ float z3[16];
    __shared__ float cntS;
    int g = blockIdx.x;
    int t = threadIdx.x;
    if (t == 0) {
        int lo = 0, hi = N;
        while (lo < hi) { int mid = (lo + hi) >> 1; if (seg[mid] < g) lo = mid + 1; else hi = mid; }
        int lo2 = lo, hi2 = N;
        while (lo2 < hi2) { int mid = (lo2 + hi2) >> 1; if (seg[mid] < g + 1) lo2 = mid + 1; else hi2 = mid; }
        cntS = fmaxf((float)(lo2 - lo), 1.f);
    }
    __syncthreads();
    if (t < 128) p[t] = pool[g * 128 + t] / cntS;
    __syncthreads();
    {
        float acc = db1[t];
        for (int k = 0; k < 128; k++) acc += p[k] * dw1[k * D1 + t];
        z1[t] = fmaxf(acc, 0.f);
    }
    __syncthreads();
    if (t < 128) {
        float acc = db2[t];
        for (int k = 0; k < 256; k++) acc += z1[k] * dw2[k * D2 + t];
        z2[t] = fmaxf(acc, 0.f);
    }
    __syncthreads();
    if (t < NCLS) {
        float acc = db3[t];
        for (int k = 0; k < 128; k++) acc += z2[k] * dw3[k * NCLS + t];
        z3[t] = acc;
    }
    __syncthreads();
    if (t == 0) {
        float mx = -1e30f;
        for (int j = 0; j < NCLS; j++) mx = fmaxf(mx, z3[j]);
        float sum = 0.f;
        float e[NCLS];
        for (int j = 0; j < NCLS; j++) { e[j] = expf(z3[j] - mx); sum += e[j]; }
        for (int j = 0; j < NCLS; j++) out[g * NCLS + j] = e[j] / sum;
    }
}

// ---------------- launch ----------------

extern "C" void kernel_launch(void* const* d_in, const int* in_sizes, int n_in,
                              void* d_out, int out_size, void* d_ws, size_t ws_size,
                              hipStream_t stream) {
    const float* x    = (const float*)d_in[0];
    const int* erow   = (const int*)d_in[1];
    const int* ecol   = (const int*)d_in[2];
    const int* seg    = (const int*)d_in[3];
    const float* w1   = (const float*)d_in[4];
    const float* b1   = (const float*)d_in[5];
    const float* w2   = (const float*)d_in[6];
    const float* b2   = (const float*)d_in[7];
    const float* w3   = (const float*)d_in[8];
    const float* b3   = (const float*)d_in[9];
    const float* g1   = (const float*)d_in[10];
    const float* be1  = (const float*)d_in[11];
    const float* m1   = (const float*)d_in[12];
    const float* v1   = (const float*)d_in[13];
    const float* g2   = (const float*)d_in[14];
    const float* be2  = (const float*)d_in[15];
    const float* m2   = (const float*)d_in[16];
    const float* v2   = (const float*)d_in[17];
    const float* g3   = (const float*)d_in[18];
    const float* be3  = (const float*)d_in[19];
    const float* m3   = (const float*)d_in[20];
    const float* v3   = (const float*)d_in[21];
    const float* dw1  = (const float*)d_in[22];
    const float* db1  = (const float*)d_in[23];
    const float* dw2  = (const float*)d_in[24];
    const float* db2  = (const float*)d_in[25];
    const float* dw3  = (const float*)d_in[26];
    const float* db3  = (const float*)d_in[27];
    float* out = (float*)d_out;

    const int N = in_sizes[3];
    const int E = in_sizes[1];

    char* ws = (char*)d_ws;
    size_t off = 0;
    auto alloc = [&](size_t bytes) -> char* {
        off = (off + 255) & ~(size_t)255;
        char* p = ws + off;
        off += bytes;
        return p;
    };
    int* cnt       = (int*)alloc((size_t)N * 4);
    int* cursor    = (int*)alloc((size_t)N * 4);
    int* row_start = (int*)alloc((size_t)N * 4);
    int* partial   = (int*)alloc(1024 * 4);
    int* csr       = (int*)alloc((size_t)E * 4);
    float* agg     = (float*)alloc((size_t)N * 128 * 4);
    float* ha      = (float*)alloc((size_t)N * 128 * 4);
    float* hb      = (float*)alloc((size_t)N * 128 * 4);  // also layer-1 padded X
    float* w1p     = (float*)alloc(128 * 128 * 4);
    float* pool    = (float*)alloc((size_t)NG * 128 * 4);

    hipMemsetAsync(cnt, 0, (size_t)N * 4, stream);
    hipMemsetAsync(cursor, 0, (size_t)N * 4, stream);
    hipMemsetAsync(pool, 0, (size_t)NG * 128 * 4, stream);

    const int nbScan = (N + 1023) / 1024;
    count_edges_k<<<(E + 255) / 256, 256, 0, stream>>>(erow, E, cnt);
    scan_partial_k<<<nbScan, 256, 0, stream>>>(cnt, N, partial);
    scan_partials_serial_k<<<1, 64, 0, stream>>>(partial, nbScan);
    scan_final_k<<<nbScan, 1024, 0, stream>>>(cnt, N, partial, row_start);
    fill_csr_k<<<(E + 255) / 256, 256, 0, stream>>>(erow, ecol, E, row_start, cursor, csr);

    const int aggGrid = (N + 3) / 4;
    const int gemmGrid = (N + 63) / 64;

    // layer 1: build padded X in hb = [x(50)|0|agg(50)|0], padded W; K=128
    copyx_k<<<(N * 64 + 255) / 256, 256, 0, stream>>>(x, hb, N);
    w1pad_k<<<(128 * 128) / 256, 256, 0, stream>>>(w1, w1p);
    aggregate50_k<<<aggGrid, 256, 0, stream>>>(x, row_start, cnt, csr, N, hb);
    gemm_fused_k<4><<<gemmGrid, 256, 0, stream>>>(hb, hb + 64, w1p, b1, g1, be1, m1, v1, N, ha);
    // layer 2: K=256
    aggregate128_k<<<aggGrid, 256, 0, stream>>>(ha, row_start, cnt, csr, N, agg);
    gemm_fused_k<8><<<gemmGrid, 256, 0, stream>>>(ha, agg, w2, b2, g2, be2, m2, v2, N, hb);
    // layer 3: K=256
    aggregate128_k<<<aggGrid, 256, 0, stream>>>(hb, row_start, cnt, csr, N, agg);
    gemm_fused_k<8><<<gemmGrid, 256, 0, stream>>>(hb, agg, w3, b3, g3, be3, m3, v3, N, ha);

    // pooling + head
    pool_k<<<(N + 63) / 64, 128, 0, stream>>>(ha, seg, N, pool);
    head_k<<<NG, 256, 0, stream>>>(pool, seg, N, dw1, db1, dw2, db2, dw3, db3, out);
}

// Round 7
// 734.258 us; speedup vs baseline: 3.0510x; 1.9785x over previous
//
#include <hip/hip_runtime.h>

static constexpr int D1   = 256;
static constexpr int D2   = 128;
static constexpr int NCLS = 10;
static constexpr int NG   = 64;

using short8 = __attribute__((ext_vector_type(8))) short;
using f32x4  = __attribute__((ext_vector_type(4))) float;

__device__ __forceinline__ float b2f(unsigned short u) {
    union { unsigned int i; float f; } c;
    c.i = ((unsigned int)u) << 16;
    return c.f;
}
__device__ __forceinline__ unsigned short f2b(float f) {
    union { float f; unsigned int i; } c;
    c.f = f;
    unsigned int u = c.i;
    return (unsigned short)((u + 0x7fffu + ((u >> 16) & 1u)) >> 16);  // RNE
}

// ---------------- CSR build ----------------

__global__ void count_edges_k(const int* __restrict__ row, int E, int* __restrict__ cnt) {
    int e = blockIdx.x * 256 + threadIdx.x;
    if (e < E) atomicAdd(&cnt[row[e]], 1);
}

__global__ void scan_partial_k(const int* __restrict__ cnt, int N, int* __restrict__ partial) {
    __shared__ int s[256];
    int base = blockIdx.x * 1024;
    int sum = 0;
    for (int i = threadIdx.x; i < 1024; i += 256) {
        int idx = base + i;
        if (idx < N) sum += cnt[idx];
    }
    s[threadIdx.x] = sum;
    __syncthreads();
    for (int st = 128; st > 0; st >>= 1) {
        if (threadIdx.x < st) s[threadIdx.x] += s[threadIdx.x + st];
        __syncthreads();
    }
    if (threadIdx.x == 0) partial[blockIdx.x] = s[0];
}

__global__ void scan_partials_serial_k(int* partial, int nb) {
    if (threadIdx.x == 0 && blockIdx.x == 0) {
        int acc = 0;
        for (int i = 0; i < nb; i++) { int v = partial[i]; partial[i] = acc; acc += v; }
    }
}

__global__ void scan_final_k(const int* __restrict__ cnt, int N, const int* __restrict__ partial,
                             int* __restrict__ row_start) {
    __shared__ int s[2][1024];
    int t = threadIdx.x;
    int idx = blockIdx.x * 1024 + t;
    int v = (idx < N) ? cnt[idx] : 0;
    s[0][t] = v;
    __syncthreads();
    int cur = 0;
    for (int st = 1; st < 1024; st <<= 1) {
        int val = s[cur][t];
        if (t >= st) val += s[cur][t - st];
        s[cur ^ 1][t] = val;
        __syncthreads();
        cur ^= 1;
    }
    if (idx < N) row_start[idx] = partial[blockIdx.x] + s[cur][t] - v;  // exclusive
}

__global__ void fill_csr_k(const int* __restrict__ row, const int* __restrict__ col, int E,
                           const int* __restrict__ row_start, int* __restrict__ cursor,
                           int* __restrict__ csr) {
    int e = blockIdx.x * 256 + threadIdx.x;
    if (e < E) {
        int r = row[e];
        int p = atomicAdd(&cursor[r], 1);
        csr[row_start[r] + p] = col[e];
    }
}

// ---------------- layer-1 prep: pad x to [N][64] bf16; pad w1 to [128][128] f32 ----------------

__global__ void copyx_k(const float* __restrict__ x, unsigned short* __restrict__ xp, int N) {
    int idx = blockIdx.x * 256 + threadIdx.x;  // N*32 threads, 2 cols each
    if (idx >= N * 32) return;
    int i = idx >> 5, c2 = idx & 31;
    unsigned int o = 0;
    if (c2 < 25) {
        o = (unsigned int)f2b(x[(size_t)i * 50 + 2 * c2]) |
            ((unsigned int)f2b(x[(size_t)i * 50 + 2 * c2 + 1]) << 16);
    }
    *reinterpret_cast<unsigned int*>(xp + (size_t)i * 64 + 2 * c2) = o;
}

// wp[128][128]: rows 0-49 = w1 rows 0-49 (x part), rows 64-113 = w1 rows 50-99 (agg part), else 0
__global__ void w1pad_k(const float* __restrict__ w1, float* __restrict__ wp) {
    int idx = blockIdx.x * 256 + threadIdx.x;  // 128*128
    int k = idx >> 7, j = idx & 127;
    float v = 0.f;
    if (k < 50) v = w1[k * 128 + j];
    else if (k >= 64 && k < 114) v = w1[(k - 14) * 128 + j];
    wp[idx] = v;
}

// W [K][128] f32 -> Wf bf16 in B-fragment order for mfma_f32_16x16x32_bf16:
// Wf[((n*KT + t)*64 + l)*8 + j] = W[t*32 + (l>>4)*8 + j][n*16 + (l&15)]
__global__ void wf_k(const float* __restrict__ W, int KT, unsigned short* __restrict__ Wf) {
    int idx = blockIdx.x * 256 + threadIdx.x;
    if (idx >= KT * 4096) return;
    int j = idx & 7;
    int l = (idx >> 3) & 63;
    int rest = idx >> 9;
    int t = rest % KT;
    int n = rest / KT;
    int k = t * 32 + (l >> 4) * 8 + j;
    int col = n * 16 + (l & 15);
    Wf[idx] = f2b(W[(size_t)k * 128 + col]);
}

// ---------------- mean aggregation (wave per row) ----------------

// FIN=50: reads f32 x, writes padded bf16 agg half [N][64] (cols 50-63 zero)
__global__ __launch_bounds__(256) void aggregate50_k(const float* __restrict__ x,
                                                     const int* __restrict__ row_start,
                                                     const int* __restrict__ cnt,
                                                     const int* __restrict__ csr, int N,
                                                     unsigned short* __restrict__ aggp) {
    int wave = threadIdx.x >> 6;
    int lane = threadIdx.x & 63;
    int i = blockIdx.x * 4 + wave;
    if (i >= N) return;
    int start = row_start[i];
    int deg = cnt[i];
    float acc = 0.f;
    for (int base = 0; base < deg; base += 64) {
        int nch = min(64, deg - base);
        int c = (base + lane < deg) ? csr[start + base + lane] : 0;
        for (int j = 0; j < nch; j++) {
            int cj = __shfl(c, j, 64);
            if (lane < 50) acc += x[(size_t)cj * 50 + lane];
        }
    }
    float inv = 1.f / fmaxf((float)deg, 1.f);
    aggp[(size_t)i * 64 + lane] = (lane < 50) ? f2b(acc * inv) : (unsigned short)0;
}

// FIN=128 bf16: lane holds cols 2l,2l+1 (one uint = 2 bf16; 256B per neighbor row)
__global__ __launch_bounds__(256) void aggregate128b_k(const unsigned short* __restrict__ x,
                                                       const int* __restrict__ row_start,
                                                       const int* __restrict__ cnt,
                                                       const int* __restrict__ csr, int N,
                                                       unsigned short* __restrict__ agg) {
    int wave = threadIdx.x >> 6;
    int lane = threadIdx.x & 63;
    int i = blockIdx.x * 4 + wave;
    if (i >= N) return;
    int start = row_start[i];
    int deg = cnt[i];
    float ax = 0.f, ay = 0.f;
    for (int base = 0; base < deg; base += 64) {
        int nch = min(64, deg - base);
        int c = (base + lane < deg) ? csr[start + base + lane] : 0;
        for (int j = 0; j < nch; j++) {
            int cj = __shfl(c, j, 64);
            unsigned int v = *reinterpret_cast<const unsigned int*>(x + (size_t)cj * 128 + 2 * lane);
            ax += b2f((unsigned short)(v & 0xffffu));
            ay += b2f((unsigned short)(v >> 16));
        }
    }
    float inv = 1.f / fmaxf((float)deg, 1.f);
    unsigned int o = (unsigned int)f2b(ax * inv) | ((unsigned int)f2b(ay * inv) << 16);
    *reinterpret_cast<unsigned int*>(agg + (size_t)i * 128 + 2 * lane) = o;
}

// ---------------- MFMA GEMM + fused l2norm/relu/BN epilogue ----------------
// out[N,128] = bn(relu(l2norm([A|B] @ W + bias))), A,B bf16 [N][KT*16], W via Wf.
// Block: 64 rows; wave w owns rows rowBase+w*16..+15. No LDS. 8 col-tiles of 16.
// A-frag: lane l holds A[row= l&15][k = (l>>4)*8 + j], contiguous 16B load.
// C-layout (verified): col = lane&15, row = (lane>>4)*4 + reg.

template <int KT>  // K = KT*32; halves A,B each KT*16 wide
__global__ __launch_bounds__(256) void gemm_mfma_k(
    const unsigned short* __restrict__ A, const unsigned short* __restrict__ B,
    const unsigned short* __restrict__ Wf, const float* __restrict__ bias,
    const float* __restrict__ gamma, const float* __restrict__ beta,
    const float* __restrict__ mean, const float* __restrict__ var,
    int N, unsigned short* __restrict__ out) {
    constexpr int S = KT * 16;
    const int tid = threadIdx.x;
    const int l   = tid & 63;
    const int w   = tid >> 6;
    const int lr  = l & 15;
    const int hk  = l >> 4;
    const int rowBase = blockIdx.x * 64 + w * 16;

    int arow = rowBase + lr;
    if (arow > N - 1) arow = N - 1;  // clamp: loads valid, stores guarded
    const unsigned short* pa = A + (size_t)arow * S + hk * 8;
    const unsigned short* pb = B + (size_t)arow * S + hk * 8;

    f32x4 acc[8] = {};

#pragma unroll
    for (int t = 0; t < KT; ++t) {
        const unsigned short* src = (t < KT / 2) ? (pa + t * 32) : (pb + (t - KT / 2) * 32);
        short8 af = *reinterpret_cast<const short8*>(src);
#pragma unroll
        for (int n = 0; n < 8; ++n) {
            short8 bf = *reinterpret_cast<const short8*>(Wf + ((size_t)(n * KT + t) * 64 + l) * 8);
            acc[n] = __builtin_amdgcn_mfma_f32_16x16x32_bf16(af, bf, acc[n], 0, 0, 0);
        }
    }

    // epilogue params for this lane's 8 columns
    float bs[8], mu[8], sc[8], bt[8];
#pragma unroll
    for (int n = 0; n < 8; ++n) {
        int col = n * 16 + lr;
        bs[n] = bias[col];
        mu[n] = mean[col];
        sc[n] = rsqrtf(var[col] + 1e-3f) * gamma[col];
        bt[n] = beta[col];
    }
#pragma unroll
    for (int i = 0; i < 4; ++i) {
        int gr = rowBase + hk * 4 + i;
        float a[8];
        float ss = 0.f;
#pragma unroll
        for (int n = 0; n < 8; ++n) { a[n] = acc[n][i] + bs[n]; ss += a[n] * a[n]; }
        // row's 128 cols live in the 16 lanes sharing hk -> 4-step xor reduce
        ss += __shfl_xor(ss, 1, 64);
        ss += __shfl_xor(ss, 2, 64);
        ss += __shfl_xor(ss, 4, 64);
        ss += __shfl_xor(ss, 8, 64);
        float rs = rsqrtf(fmaxf(ss, 1e-12f));
        if (gr < N) {
#pragma unroll
            for (int n = 0; n < 8; ++n) {
                float v = fmaxf(a[n] * rs, 0.f);
                v = (v - mu[n]) * sc[n] + bt[n];
                out[(size_t)gr * 128 + n * 16 + lr] = f2b(v);
            }
        }
    }
}

// ---------------- segment (graph) pooling ----------------

__global__ __launch_bounds__(128) void pool_k(const unsigned short* __restrict__ h,
                                              const int* __restrict__ seg, int N,
                                              float* __restrict__ pool) {
    int tx = threadIdx.x;  // feature 0..127
    int r0 = blockIdx.x * 64;
    int rend = min(r0 + 64, N);
    if (r0 >= N) return;
    int cur = seg[r0];
    float sum = 0.f;
    for (int r = r0; r < rend; r++) {
        int s = seg[r];
        float v = b2f(h[(size_t)r * 128 + tx]);
        if (s != cur) {
            atomicAdd(&pool[cur * 128 + tx], sum);
            cur = s;
            sum = v;
        } else {
            sum += v;
        }
    }
    atomicAdd(&pool[cur * 128 + tx], sum);
}

// ---------------- dense head: 64 blocks, one graph each ----------------

__global__ __launch_bounds__(256) void head_k(const float* __restrict__ pool,
                                              const int* __restrict__ seg, int N,
                                              const float* __restrict__ dw1, const float* __restrict__ db1,
                                              const float* __restrict__ dw2, const float* __restrict__ db2,
                                              const float* __restrict__ dw3, const float* __restrict__ db3,
                                              float* __restrict__ out) {
    __shared__ float p[128];
    __shared__ float z1[256];
    __shared__ float z2[128];
    __shared__ float z3[16];
    __shared__ float cntS;
    int g = blockIdx.x;
    int t = threadIdx.x;
    if (t == 0) {
        int lo = 0, hi = N;
        while (lo < hi) { int mid = (lo + hi) >> 1; if (seg[mid] < g) lo = mid + 1; else hi = mid; }
        int lo2 = lo, hi2 = N;
        while (lo2 < hi2) { int mid = (lo2 + hi2) >> 1; if (seg[mid] < g + 1) lo2 = mid + 1; else hi2 = mid; }
        cntS = fmaxf((float)(lo2 - lo), 1.f);
    }
    __syncthreads();
    if (t < 128) p[t] = pool[g * 128 + t] / cntS;
    __syncthreads();
    {
        float acc = db1[t];
        for (int k = 0; k < 128; k++) acc += p[k] * dw1[k * D1 + t];
        z1[t] = fmaxf(acc, 0.f);
    }
    __syncthreads();
    if (t < 128) {
        float acc = db2[t];
        for (int k = 0; k < 256; k++) acc += z1[k] * dw2[k * D2 + t];
        z2[t] = fmaxf(acc, 0.f);
    }
    __syncthreads();
    if (t < NCLS) {
        float acc = db3[t];
        for (int k = 0; k < 128; k++) acc += z2[k] * dw3[k * NCLS + t];
        z3[t] = acc;
    }
    __syncthreads();
    if (t == 0) {
        float mx = -1e30f;
        for (int j = 0; j < NCLS; j++) mx = fmaxf(mx, z3[j]);
        float sum = 0.f;
        float e[NCLS];
        for (int j = 0; j < NCLS; j++) { e[j] = expf(z3[j] - mx); sum += e[j]; }
        for (int j = 0; j < NCLS; j++) out[g * NCLS + j] = e[j] / sum;
    }
}

// ---------------- launch ----------------

extern "C" void kernel_launch(void* const* d_in, const int* in_sizes, int n_in,
                              void* d_out, int out_size, void* d_ws, size_t ws_size,
                              hipStream_t stream) {
    const float* x    = (const float*)d_in[0];
    const int* erow   = (const int*)d_in[1];
    const int* ecol   = (const int*)d_in[2];
    const int* seg    = (const int*)d_in[3];
    const float* w1   = (const float*)d_in[4];
    const float* b1   = (const float*)d_in[5];
    const float* w2   = (const float*)d_in[6];
    const float* b2   = (const float*)d_in[7];
    const float* w3   = (const float*)d_in[8];
    const float* b3   = (const float*)d_in[9];
    const float* g1   = (const float*)d_in[10];
    const float* be1  = (const float*)d_in[11];
    const float* m1   = (const float*)d_in[12];
    const float* v1   = (const float*)d_in[13];
    const float* g2   = (const float*)d_in[14];
    const float* be2  = (const float*)d_in[15];
    const float* m2   = (const float*)d_in[16];
    const float* v2   = (const float*)d_in[17];
    const float* g3   = (const float*)d_in[18];
    const float* be3  = (const float*)d_in[19];
    const float* m3   = (const float*)d_in[20];
    const float* v3   = (const float*)d_in[21];
    const float* dw1  = (const float*)d_in[22];
    const float* db1  = (const float*)d_in[23];
    const float* dw2  = (const float*)d_in[24];
    const float* db2  = (const float*)d_in[25];
    const float* dw3  = (const float*)d_in[26];
    const float* db3  = (const float*)d_in[27];
    float* out = (float*)d_out;

    const int N = in_sizes[3];
    const int E = in_sizes[1];

    char* ws = (char*)d_ws;
    size_t off = 0;
    auto alloc = [&](size_t bytes) -> char* {
        off = (off + 255) & ~(size_t)255;
        char* p = ws + off;
        off += bytes;
        return p;
    };
    int* cnt        = (int*)alloc((size_t)N * 4);
    int* cursor     = (int*)alloc((size_t)N * 4);
    int* row_start  = (int*)alloc((size_t)N * 4);
    int* partial    = (int*)alloc(1024 * 4);
    int* csr        = (int*)alloc((size_t)E * 4);
    unsigned short* xpad = (unsigned short*)alloc((size_t)N * 64 * 2);
    unsigned short* aggp = (unsigned short*)alloc((size_t)N * 64 * 2);
    unsigned short* hA   = (unsigned short*)alloc((size_t)N * 128 * 2);
    unsigned short* hB   = (unsigned short*)alloc((size_t)N * 128 * 2);
    unsigned short* aggb = (unsigned short*)alloc((size_t)N * 128 * 2);
    float* w1p      = (float*)alloc(128 * 128 * 4);
    unsigned short* wf1 = (unsigned short*)alloc(128 * 128 * 2);
    unsigned short* wf2 = (unsigned short*)alloc(256 * 128 * 2);
    unsigned short* wf3 = (unsigned short*)alloc(256 * 128 * 2);
    float* pool     = (float*)alloc((size_t)NG * 128 * 4);

    hipMemsetAsync(cnt, 0, (size_t)N * 4, stream);
    hipMemsetAsync(cursor, 0, (size_t)N * 4, stream);
    hipMemsetAsync(pool, 0, (size_t)NG * 128 * 4, stream);

    const int nbScan = (N + 1023) / 1024;
    count_edges_k<<<(E + 255) / 256, 256, 0, stream>>>(erow, E, cnt);
    scan_partial_k<<<nbScan, 256, 0, stream>>>(cnt, N, partial);
    scan_partials_serial_k<<<1, 64, 0, stream>>>(partial, nbScan);
    scan_final_k<<<nbScan, 1024, 0, stream>>>(cnt, N, partial, row_start);
    fill_csr_k<<<(E + 255) / 256, 256, 0, stream>>>(erow, ecol, E, row_start, cursor, csr);

    // weight prep
    w1pad_k<<<(128 * 128) / 256, 256, 0, stream>>>(w1, w1p);
    wf_k<<<(4 * 4096) / 256, 256, 0, stream>>>(w1p, 4, wf1);
    wf_k<<<(8 * 4096) / 256, 256, 0, stream>>>(w2, 8, wf2);
    wf_k<<<(8 * 4096) / 256, 256, 0, stream>>>(w3, 8, wf3);
    copyx_k<<<(N * 32 + 255) / 256, 256, 0, stream>>>(x, xpad, N);

    const int aggGrid = (N + 3) / 4;
    const int gemmGrid = (N + 63) / 64;

    // layer 1 (K=128 padded)
    aggregate50_k<<<aggGrid, 256, 0, stream>>>(x, row_start, cnt, csr, N, aggp);
    gemm_mfma_k<4><<<gemmGrid, 256, 0, stream>>>(xpad, aggp, wf1, b1, g1, be1, m1, v1, N, hA);
    // layer 2 (K=256)
    aggregate128b_k<<<aggGrid, 256, 0, stream>>>(hA, row_start, cnt, csr, N, aggb);
    gemm_mfma_k<8><<<gemmGrid, 256, 0, stream>>>(hA, aggb, wf2, b2, g2, be2, m2, v2, N, hB);
    // layer 3 (K=256)
    aggregate128b_k<<<aggGrid, 256, 0, stream>>>(hB, row_start, cnt, csr, N, aggb);
    gemm_mfma_k<8><<<gemmGrid, 256, 0, stream>>>(hB, aggb, wf3, b3, g3, be3, m3, v3, N, hA);

    // pooling + head
    pool_k<<<(N + 63) / 64, 128, 0, stream>>>(hA, seg, N, pool);
    head_k<<<NG, 256, 0, stream>>>(pool, seg, N, dw1, db1, dw2, db2, dw3, db3, out);
}

// Round 10
// 560.668 us; speedup vs baseline: 3.9956x; 1.3096x over previous
//
#include <hip/hip_runtime.h>

static constexpr int D1   = 256;
static constexpr int D2   = 128;
static constexpr int NCLS = 10;
static constexpr int NG   = 64;

using short8 = __attribute__((ext_vector_type(8))) short;
using f32x4  = __attribute__((ext_vector_type(4))) float;

__device__ __forceinline__ float b2f(unsigned short u) {
    union { unsigned int i; float f; } c;
    c.i = ((unsigned int)u) << 16;
    return c.f;
}
__device__ __forceinline__ unsigned short f2b(float f) {
    union { float f; unsigned int i; } c;
    c.f = f;
    unsigned int u = c.i;
    return (unsigned short)((u + 0x7fffu + ((u >> 16) & 1u)) >> 16);  // RNE
}

// ---------------- CSR build ----------------

// counts + per-edge slot (atomicAdd return) so fill needs no atomics
__global__ void count_edges_k(const int* __restrict__ row, int E, int* __restrict__ cnt,
                              int* __restrict__ eslot) {
    int e = blockIdx.x * 256 + threadIdx.x;
    if (e < E) eslot[e] = atomicAdd(&cnt[row[e]], 1);
}

__global__ void scan_partial_k(const int* __restrict__ cnt, int N, int* __restrict__ partial) {
    __shared__ int s[256];
    int base = blockIdx.x * 1024;
    int sum = 0;
    for (int i = threadIdx.x; i < 1024; i += 256) {
        int idx = base + i;
        if (idx < N) sum += cnt[idx];
    }
    s[threadIdx.x] = sum;
    __syncthreads();
    for (int st = 128; st > 0; st >>= 1) {
        if (threadIdx.x < st) s[threadIdx.x] += s[threadIdx.x + st];
        __syncthreads();
    }
    if (threadIdx.x == 0) partial[blockIdx.x] = s[0];
}

__global__ void scan_partials_serial_k(int* partial, int nb) {
    if (threadIdx.x == 0 && blockIdx.x == 0) {
        int acc = 0;
        for (int i = 0; i < nb; i++) { int v = partial[i]; partial[i] = acc; acc += v; }
    }
}

__global__ void scan_final_k(const int* __restrict__ cnt, int N, const int* __restrict__ partial,
                             int* __restrict__ row_start) {
    __shared__ int s[2][1024];
    int t = threadIdx.x;
    int idx = blockIdx.x * 1024 + t;
    int v = (idx < N) ? cnt[idx] : 0;
    s[0][t] = v;
    __syncthreads();
    int cur = 0;
    for (int st = 1; st < 1024; st <<= 1) {
        int val = s[cur][t];
        if (t >= st) val += s[cur][t - st];
        s[cur ^ 1][t] = val;
        __syncthreads();
        cur ^= 1;
    }
    if (idx < N) row_start[idx] = partial[blockIdx.x] + s[cur][t] - v;  // exclusive
}

// pure scatter store (no atomics)
__global__ void fill_csr_k(const int* __restrict__ row, const int* __restrict__ col,
                           const int* __restrict__ eslot, int E,
                           const int* __restrict__ row_start, int* __restrict__ csr) {
    int e = blockIdx.x * 256 + threadIdx.x;
    if (e < E) csr[row_start[row[e]] + eslot[e]] = col[e];
}

// ---------------- layer-1 prep: pad x to [N][64] bf16; pad w1 to [128][128] f32 ----------------

__global__ void copyx_k(const float* __restrict__ x, unsigned short* __restrict__ xp, int N) {
    int idx = blockIdx.x * 256 + threadIdx.x;  // N*32 threads, 2 cols each
    if (idx >= N * 32) return;
    int i = idx >> 5, c2 = idx & 31;
    unsigned int o = 0;
    if (c2 < 25) {
        o = (unsigned int)f2b(x[(size_t)i * 50 + 2 * c2]) |
            ((unsigned int)f2b(x[(size_t)i * 50 + 2 * c2 + 1]) << 16);
    }
    *reinterpret_cast<unsigned int*>(xp + (size_t)i * 64 + 2 * c2) = o;
}

// wp[128][128]: rows 0-49 = w1 rows 0-49 (x part), rows 64-113 = w1 rows 50-99 (agg part), else 0
__global__ void w1pad_k(const float* __restrict__ w1, float* __restrict__ wp) {
    int idx = blockIdx.x * 256 + threadIdx.x;  // 128*128
    int k = idx >> 7, j = idx & 127;
    float v = 0.f;
    if (k < 50) v = w1[k * 128 + j];
    else if (k >= 64 && k < 114) v = w1[(k - 14) * 128 + j];
    wp[idx] = v;
}

// W [K][128] f32 -> Wf bf16 in B-fragment order for mfma_f32_16x16x32_bf16:
// Wf[((n*KT + t)*64 + l)*8 + j] = W[t*32 + (l>>4)*8 + j][n*16 + (l&15)]
__global__ void wf_k(const float* __restrict__ W, int KT, unsigned short* __restrict__ Wf) {
    int idx = blockIdx.x * 256 + threadIdx.x;
    if (idx >= KT * 4096) return;
    int j = idx & 7;
    int l = (idx >> 3) & 63;
    int rest = idx >> 9;
    int t = rest % KT;
    int n = rest / KT;
    int k = t * 32 + (l >> 4) * 8 + j;
    int col = n * 16 + (l & 15);
    Wf[idx] = f2b(W[(size_t)k * 128 + col]);
}

// ---------------- mean aggregation (wave per row, 2 neighbors per iteration) ----------------

// layer 1: reads bf16 xpad [N][64] (cols 50-63 zero); lanes 0-31 even neighbor, 32-63 odd
__global__ __launch_bounds__(256) void aggregate50b_k(const unsigned short* __restrict__ xp,
                                                      const int* __restrict__ row_start,
                                                      const int* __restrict__ cnt,
                                                      const int* __restrict__ csr, int N,
                                                      unsigned short* __restrict__ aggp) {
    int wave = threadIdx.x >> 6;
    int lane = threadIdx.x & 63;
    int half = lane >> 5;
    int fl   = lane & 31;  // feature pair: cols 2fl, 2fl+1
    int i = blockIdx.x * 4 + wave;
    if (i >= N) return;
    int start = row_start[i];
    int deg = cnt[i];
    float ax = 0.f, ay = 0.f;
    for (int base = 0; base < deg; base += 64) {
        int nch = min(64, deg - base);
        int c = (base + lane < deg) ? csr[start + base + lane] : 0;
        int j = 0;
        for (; j + 2 <= nch; j += 2) {
            int cj = __shfl(c, j + half, 64);
            unsigned int v = *reinterpret_cast<const unsigned int*>(xp + (size_t)cj * 64 + 2 * fl);
            ax += b2f((unsigned short)(v & 0xffffu));
            ay += b2f((unsigned short)(v >> 16));
        }
        if (j < nch) {
            int cj = __shfl(c, j, 64);
            if (half == 0) {
                unsigned int v = *reinterpret_cast<const unsigned int*>(xp + (size_t)cj * 64 + 2 * fl);
                ax += b2f((unsigned short)(v & 0xffffu));
                ay += b2f((unsigned short)(v >> 16));
            }
        }
    }
    ax += __shfl_xor(ax, 32, 64);
    ay += __shfl_xor(ay, 32, 64);
    if (half == 0) {
        float inv = 1.f / fmaxf((float)deg, 1.f);
        unsigned int o = (unsigned int)f2b(ax * inv) | ((unsigned int)f2b(ay * inv) << 16);
        *reinterpret_cast<unsigned int*>(aggp + (size_t)i * 64 + 2 * fl) = o;
    }
}

// layers 2/3: bf16 [N][128]; uint2 (4 bf16) per lane, 2 neighbors per iteration
__global__ __launch_bounds__(256) void aggregate128c_k(const unsigned short* __restrict__ x,
                                                       const int* __restrict__ row_start,
                                                       const int* __restrict__ cnt,
                                                       const int* __restrict__ csr, int N,
                                                       unsigned short* __restrict__ agg) {
    int wave = threadIdx.x >> 6;
    int lane = threadIdx.x & 63;
    int half = lane >> 5;
    int fl   = lane & 31;  // cols 4fl .. 4fl+3
    int i = blockIdx.x * 4 + wave;
    if (i >= N) return;
    int start = row_start[i];
    int deg = cnt[i];
    float a0 = 0.f, a1 = 0.f, a2 = 0.f, a3 = 0.f;
    for (int base = 0; base < deg; base += 64) {
        int nch = min(64, deg - base);
        int c = (base + lane < deg) ? csr[start + base + lane] : 0;
        int j = 0;
        for (; j + 2 <= nch; j += 2) {
            int cj = __shfl(c, j + half, 64);
            uint2 v = *reinterpret_cast<const uint2*>(x + (size_t)cj * 128 + 4 * fl);
            a0 += b2f((unsigned short)(v.x & 0xffffu));
            a1 += b2f((unsigned short)(v.x >> 16));
            a2 += b2f((unsigned short)(v.y & 0xffffu));
            a3 += b2f((unsigned short)(v.y >> 16));
        }
        if (j < nch) {
            int cj = __shfl(c, j, 64);
            if (half == 0) {
                uint2 v = *reinterpret_cast<const uint2*>(x + (size_t)cj * 128 + 4 * fl);
                a0 += b2f((unsigned short)(v.x & 0xffffu));
                a1 += b2f((unsigned short)(v.x >> 16));
                a2 += b2f((unsigned short)(v.y & 0xffffu));
                a3 += b2f((unsigned short)(v.y >> 16));
            }
        }
    }
    a0 += __shfl_xor(a0, 32, 64);
    a1 += __shfl_xor(a1, 32, 64);
    a2 += __shfl_xor(a2, 32, 64);
    a3 += __shfl_xor(a3, 32, 64);
    if (half == 0) {
        float inv = 1.f / fmaxf((float)deg, 1.f);
        uint2 o;
        o.x = (unsigned int)f2b(a0 * inv) | ((unsigned int)f2b(a1 * inv) << 16);
        o.y = (unsigned int)f2b(a2 * inv) | ((unsigned int)f2b(a3 * inv) << 16);
        *reinterpret_cast<uint2*>(agg + (size_t)i * 128 + 4 * fl) = o;
    }
}

// ---------------- MFMA GEMM + fused l2norm/relu/BN epilogue ----------------
// out[N,128] = bn(relu(l2norm([A|B] @ W + bias))), A,B bf16 [N][KT*16], W via Wf.
// A-frag: lane l holds A[row=l&15][k=(l>>4)*8+j]. C-layout: col=lane&15, row=(lane>>4)*4+reg.

template <int KT>  // K = KT*32; halves A,B each KT*16 wide
__global__ __launch_bounds__(256) void gemm_mfma_k(
    const unsigned short* __restrict__ A, const unsigned short* __restrict__ B,
    const unsigned short* __restrict__ Wf, const float* __restrict__ bias,
    const float* __restrict__ gamma, const float* __restrict__ beta,
    const float* __restrict__ mean, const float* __restrict__ var,
    int N, unsigned short* __restrict__ out) {
    constexpr int S = KT * 16;
    const int tid = threadIdx.x;
    const int l   = tid & 63;
    const int w   = tid >> 6;
    const int lr  = l & 15;
    const int hk  = l >> 4;
    const int rowBase = blockIdx.x * 64 + w * 16;

    int arow = rowBase + lr;
    if (arow > N - 1) arow = N - 1;  // clamp: loads valid, stores guarded
    const unsigned short* pa = A + (size_t)arow * S + hk * 8;
    const unsigned short* pb = B + (size_t)arow * S + hk * 8;

    f32x4 acc[8] = {};

#pragma unroll
    for (int t = 0; t < KT; ++t) {
        const unsigned short* src = (t < KT / 2) ? (pa + t * 32) : (pb + (t - KT / 2) * 32);
        short8 af = *reinterpret_cast<const short8*>(src);
#pragma unroll
        for (int n = 0; n < 8; ++n) {
            short8 bf = *reinterpret_cast<const short8*>(Wf + ((size_t)(n * KT + t) * 64 + l) * 8);
            acc[n] = __builtin_amdgcn_mfma_f32_16x16x32_bf16(af, bf, acc[n], 0, 0, 0);
        }
    }

    float bs[8], mu[8], sc[8], bt[8];
#pragma unroll
    for (int n = 0; n < 8; ++n) {
        int col = n * 16 + lr;
        bs[n] = bias[col];
        mu[n] = mean[col];
        sc[n] = rsqrtf(var[col] + 1e-3f) * gamma[col];
        bt[n] = beta[col];
    }
#pragma unroll
    for (int i = 0; i < 4; ++i) {
        int gr = rowBase + hk * 4 + i;
        float a[8];
        float ss = 0.f;
#pragma unroll
        for (int n = 0; n < 8; ++n) { a[n] = acc[n][i] + bs[n]; ss += a[n] * a[n]; }
        ss += __shfl_xor(ss, 1, 64);
        ss += __shfl_xor(ss, 2, 64);
        ss += __shfl_xor(ss, 4, 64);
        ss += __shfl_xor(ss, 8, 64);
        float rs = rsqrtf(fmaxf(ss, 1e-12f));
        if (gr < N) {
#pragma unroll
            for (int n = 0; n < 8; ++n) {
                float v = fmaxf(a[n] * rs, 0.f);
                v = (v - mu[n]) * sc[n] + bt[n];
                out[(size_t)gr * 128 + n * 16 + lr] = f2b(v);
            }
        }
    }
}

// ---------------- segment (graph) pooling ----------------

__global__ __launch_bounds__(128) void pool_k(const unsigned short* __restrict__ h,
                                              const int* __restrict__ seg, int N,
                                              float* __restrict__ pool) {
    int tx = threadIdx.x;  // feature 0..127
    int r0 = blockIdx.x * 64;
    int rend = min(r0 + 64, N);
    if (r0 >= N) return;
    int cur = seg[r0];
    float sum = 0.f;
    for (int r = r0; r < rend; r++) {
        int s = seg[r];
        float v = b2f(h[(size_t)r * 128 + tx]);
        if (s != cur) {
            atomicAdd(&pool[cur * 128 + tx], sum);
            cur = s;
            sum = v;
        } else {
            sum += v;
        }
    }
    atomicAdd(&pool[cur * 128 + tx], sum);
}

// ---------------- dense head: 64 blocks, one graph each ----------------

__global__ __launch_bounds__(256) void head_k(const float* __restrict__ pool,
                                              const int* __restrict__ seg, int N,
                                              const float* __restrict__ dw1, const float* __restrict__ db1,
                                              const float* __restrict__ dw2, const float* __restrict__ db2,
                                              const float* __restrict__ dw3, const float* __restrict__ db3,
                                              float* __restrict__ out) {
    __shared__ float p[128];
    __shared__ float z1[256];
    __shared__ float z2[128];
    __shared__ float z3[16];
    __shared__ float cntS;
    int g = blockIdx.x;
    int t = threadIdx.x;
    if (t == 0) {
        int lo = 0, hi = N;
        while (lo < hi) { int mid = (lo + hi) >> 1; if (seg[mid] < g) lo = mid + 1; else hi = mid; }
        int lo2 = lo, hi2 = N;
        while (lo2 < hi2) { int mid = (lo2 + hi2) >> 1; if (seg[mid] < g + 1) lo2 = mid + 1; else hi2 = mid; }
        cntS = fmaxf((float)(lo2 - lo), 1.f);
    }
    __syncthreads();
    if (t < 128) p[t] = pool[g * 128 + t] / cntS;
    __syncthreads();
    {
        float acc = db1[t];
        for (int k = 0; k < 128; k++) acc += p[k] * dw1[k * D1 + t];
        z1[t] = fmaxf(acc, 0.f);
    }
    __syncthreads();
    if (t < 128) {
        float acc = db2[t];
        for (int k = 0; k < 256; k++) acc += z1[k] * dw2[k * D2 + t];
        z2[t] = fmaxf(acc, 0.f);
    }
    __syncthreads();
    if (t < NCLS) {
        float acc = db3[t];
        for (int k = 0; k < 128; k++) acc += z2[k] * dw3[k * NCLS + t];
        z3[t] = acc;
    }
    __syncthreads();
    if (t == 0) {
        float mx = -1e30f;
        for (int j = 0; j < NCLS; j++) mx = fmaxf(mx, z3[j]);
        float sum = 0.f;
        float e[NCLS];
        for (int j = 0; j < NCLS; j++) { e[j] = expf(z3[j] - mx); sum += e[j]; }
        for (int j = 0; j < NCLS; j++) out[g * NCLS + j] = e[j] / sum;
    }
}

// ---------------- launch ----------------

extern "C" void kernel_launch(void* const* d_in, const int* in_sizes, int n_in,
                              void* d_out, int out_size, void* d_ws, size_t ws_size,
                              hipStream_t stream) {
    const float* x    = (const float*)d_in[0];
    const int* erow   = (const int*)d_in[1];
    const int* ecol   = (const int*)d_in[2];
    const int* seg    = (const int*)d_in[3];
    const float* w1   = (const float*)d_in[4];
    const float* b1   = (const float*)d_in[5];
    const float* w2   = (const float*)d_in[6];
    const float* b2   = (const float*)d_in[7];
    const float* w3   = (const float*)d_in[8];
    const float* b3   = (const float*)d_in[9];
    const float* g1   = (const float*)d_in[10];
    const float* be1  = (const float*)d_in[11];
    const float* m1   = (const float*)d_in[12];
    const float* v1   = (const float*)d_in[13];
    const float* g2   = (const float*)d_in[14];
    const float* be2  = (const float*)d_in[15];
    const float* m2   = (const float*)d_in[16];
    const float* v2   = (const float*)d_in[17];
    const float* g3   = (const float*)d_in[18];
    const float* be3  = (const float*)d_in[19];
    const float* m3   = (const float*)d_in[20];
    const float* v3   = (const float*)d_in[21];
    const float* dw1  = (const float*)d_in[22];
    const float* db1  = (const float*)d_in[23];
    const float* dw2  = (const float*)d_in[24];
    const float* db2  = (const float*)d_in[25];
    const float* dw3  = (const float*)d_in[26];
    const float* db3  = (const float*)d_in[27];
    float* out = (float*)d_out;

    const int N = in_sizes[3];
    const int E = in_sizes[1];

    char* ws = (char*)d_ws;
    size_t off = 0;
    auto alloc = [&](size_t bytes) -> char* {
        off = (off + 255) & ~(size_t)255;
        char* p = ws + off;
        off += bytes;
        return p;
    };
    int* cnt        = (int*)alloc((size_t)N * 4);
    int* row_start  = (int*)alloc((size_t)N * 4);
    int* partial    = (int*)alloc(1024 * 4);
    int* csr        = (int*)alloc((size_t)E * 4);
    int* eslot      = (int*)alloc((size_t)E * 4);
    unsigned short* xpad = (unsigned short*)alloc((size_t)N * 64 * 2);
    unsigned short* aggp = (unsigned short*)alloc((size_t)N * 64 * 2);
    unsigned short* hA   = (unsigned short*)alloc((size_t)N * 128 * 2);
    unsigned short* hB   = (unsigned short*)alloc((size_t)N * 128 * 2);
    unsigned short* aggb = (unsigned short*)alloc((size_t)N * 128 * 2);
    float* w1p      = (float*)alloc(128 * 128 * 4);
    unsigned short* wf1 = (unsigned short*)alloc(128 * 128 * 2);
    unsigned short* wf2 = (unsigned short*)alloc(256 * 128 * 2);
    unsigned short* wf3 = (unsigned short*)alloc(256 * 128 * 2);
    float* pool     = (float*)alloc((size_t)NG * 128 * 4);

    hipMemsetAsync(cnt, 0, (size_t)N * 4, stream);
    hipMemsetAsync(pool, 0, (size_t)NG * 128 * 4, stream);

    const int nbScan = (N + 1023) / 1024;
    count_edges_k<<<(E + 255) / 256, 256, 0, stream>>>(erow, E, cnt, eslot);
    scan_partial_k<<<nbScan, 256, 0, stream>>>(cnt, N, partial);
    scan_partials_serial_k<<<1, 64, 0, stream>>>(partial, nbScan);
    scan_final_k<<<nbScan, 1024, 0, stream>>>(cnt, N, partial, row_start);
    fill_csr_k<<<(E + 255) / 256, 256, 0, stream>>>(erow, ecol, eslot, E, row_start, csr);

    // weight prep + x pad
    w1pad_k<<<(128 * 128) / 256, 256, 0, stream>>>(w1, w1p);
    wf_k<<<(4 * 4096) / 256, 256, 0, stream>>>(w1p, 4, wf1);
    wf_k<<<(8 * 4096) / 256, 256, 0, stream>>>(w2, 8, wf2);
    wf_k<<<(8 * 4096) / 256, 256, 0, stream>>>(w3, 8, wf3);
    copyx_k<<<(N * 32 + 255) / 256, 256, 0, stream>>>(x, xpad, N);

    const int aggGrid = (N + 3) / 4;
    const int gemmGrid = (N + 63) / 64;

    // layer 1 (K=128 padded)
    aggregate50b_k<<<aggGrid, 256, 0, stream>>>(xpad, row_start, cnt, csr, N, aggp);
    gemm_mfma_k<4><<<gemmGrid, 256, 0, stream>>>(xpad, aggp, wf1, b1, g1, be1, m1, v1, N, hA);
    // layer 2 (K=256)
    aggregate128c_k<<<aggGrid, 256, 0, stream>>>(hA, row_start, cnt, csr, N, aggb);
    gemm_mfma_k<8><<<gemmGrid, 256, 0, stream>>>(hA, aggb, wf2, b2, g2, be2, m2, v2, N, hB);
    // layer 3 (K=256)
    aggregate128c_k<<<aggGrid, 256, 0, stream>>>(hB, row_start, cnt, csr, N, aggb);
    gemm_mfma_k<8><<<gemmGrid, 256, 0, stream>>>(hB, aggb, wf3, b3, g3, be3, m3, v3, N, hA);

    // pooling + head
    pool_k<<<(N + 63) / 64, 128, 0, stream>>>(hA, seg, N, pool);
    head_k<<<NG, 256, 0, stream>>>(pool, seg, N, dw1, db1, dw2, db2, dw3, db3, out);
}

// Round 12
// 541.818 us; speedup vs baseline: 4.1346x; 1.0348x over previous
//
#include <hip/hip_runtime.h>

static constexpr int D1   = 256;
static constexpr int D2   = 128;
static constexpr int NCLS = 10;
static constexpr int NG   = 64;

using short8 = __attribute__((ext_vector_type(8))) short;
using f32x4  = __attribute__((ext_vector_type(4))) float;

__device__ __forceinline__ float b2f(unsigned short u) {
    union { unsigned int i; float f; } c;
    c.i = ((unsigned int)u) << 16;
    return c.f;
}
__device__ __forceinline__ unsigned short f2b(float f) {
    union { float f; unsigned int i; } c;
    c.f = f;
    unsigned int u = c.i;
    return (unsigned short)((u + 0x7fffu + ((u >> 16) & 1u)) >> 16);  // RNE
}

// ---------------- CSR build ----------------

// counts + per-edge slot (atomicAdd return) so fill needs no atomics
__global__ void count_edges_k(const int* __restrict__ row, int E, int* __restrict__ cnt,
                              int* __restrict__ eslot) {
    int e = blockIdx.x * 256 + threadIdx.x;
    if (e < E) eslot[e] = atomicAdd(&cnt[row[e]], 1);
}

__global__ void scan_partial_k(const int* __restrict__ cnt, int N, int* __restrict__ partial) {
    __shared__ int s[256];
    int base = blockIdx.x * 1024;
    int sum = 0;
    for (int i = threadIdx.x; i < 1024; i += 256) {
        int idx = base + i;
        if (idx < N) sum += cnt[idx];
    }
    s[threadIdx.x] = sum;
    __syncthreads();
    for (int st = 128; st > 0; st >>= 1) {
        if (threadIdx.x < st) s[threadIdx.x] += s[threadIdx.x + st];
        __syncthreads();
    }
    if (threadIdx.x == 0) partial[blockIdx.x] = s[0];
}

__global__ void scan_partials_serial_k(int* partial, int nb) {
    if (threadIdx.x == 0 && blockIdx.x == 0) {
        int acc = 0;
        for (int i = 0; i < nb; i++) { int v = partial[i]; partial[i] = acc; acc += v; }
    }
}

__global__ void scan_final_k(const int* __restrict__ cnt, int N, const int* __restrict__ partial,
                             int* __restrict__ row_start) {
    __shared__ int s[2][1024];
    int t = threadIdx.x;
    int idx = blockIdx.x * 1024 + t;
    int v = (idx < N) ? cnt[idx] : 0;
    s[0][t] = v;
    __syncthreads();
    int cur = 0;
    for (int st = 1; st < 1024; st <<= 1) {
        int val = s[cur][t];
        if (t >= st) val += s[cur][t - st];
        s[cur ^ 1][t] = val;
        __syncthreads();
        cur ^= 1;
    }
    if (idx < N) row_start[idx] = partial[blockIdx.x] + s[cur][t] - v;  // exclusive
}

// 2-pass row-range scatter (no atomics). Each pass's live csr region (~E/2*4B)
// fits a per-XCD L2; NT reads keep the streams from evicting the write lines.
__global__ void fill_csr2_k(const int* __restrict__ row, const int* __restrict__ col,
                            const int* __restrict__ eslot, int E,
                            const int* __restrict__ row_start, int* __restrict__ csr,
                            int rlo, int rhi) {
    int e = blockIdx.x * 256 + threadIdx.x;
    if (e < E) {
        int r = __builtin_nontemporal_load(row + e);
        if (r >= rlo && r < rhi) {
            int c = __builtin_nontemporal_load(col + e);
            int s = __builtin_nontemporal_load(eslot + e);
            csr[row_start[r] + s] = c;
        }
    }
}

// ---------------- prep: pad x to [N][64] bf16; W -> bf16 fragment order ----------------

__global__ void copyx_k(const float* __restrict__ x, unsigned short* __restrict__ xp, int N) {
    int idx = blockIdx.x * 256 + threadIdx.x;  // N*32 threads, 2 cols each
    if (idx >= N * 32) return;
    int i = idx >> 5, c2 = idx & 31;
    unsigned int o = 0;
    if (c2 < 25) {
        o = (unsigned int)f2b(x[(size_t)i * 50 + 2 * c2]) |
            ((unsigned int)f2b(x[(size_t)i * 50 + 2 * c2 + 1]) << 16);
    }
    *reinterpret_cast<unsigned int*>(xp + (size_t)i * 64 + 2 * c2) = o;
}

// W [K][128] f32 -> Wf bf16 in B-fragment order for mfma_f32_16x16x32_bf16:
// Wf[((n*KT + t)*64 + l)*8 + j] = W[t*32 + (l>>4)*8 + j][n*16 + (l&15)]
__global__ void wf_k(const float* __restrict__ W, int KT, unsigned short* __restrict__ Wf) {
    int idx = blockIdx.x * 256 + threadIdx.x;
    if (idx >= KT * 4096) return;
    int j = idx & 7;
    int l = (idx >> 3) & 63;
    int rest = idx >> 9;
    int t = rest % KT;
    int n = rest / KT;
    int k = t * 32 + (l >> 4) * 8 + j;
    int col = n * 16 + (l & 15);
    Wf[idx] = f2b(W[(size_t)k * 128 + col]);
}

// layer-1 variant: fuses w1 row padding (rows 0-49 -> x part at k 0-49, rows 50-99 -> agg part at k 64-113)
__global__ void wf1p_k(const float* __restrict__ w1, unsigned short* __restrict__ Wf) {
    int idx = blockIdx.x * 256 + threadIdx.x;  // KT=4 -> 16384
    if (idx >= 4 * 4096) return;
    int j = idx & 7;
    int l = (idx >> 3) & 63;
    int rest = idx >> 9;
    int t = rest % 4;
    int n = rest / 4;
    int k = t * 32 + (l >> 4) * 8 + j;     // 0..127
    int col = n * 16 + (l & 15);
    float v = 0.f;
    if (k < 50) v = w1[k * 128 + col];
    else if (k >= 64 && k < 114) v = w1[(k - 14) * 128 + col];
    Wf[idx] = f2b(v);
}

// ---------------- mean aggregation (wave per row, 4 neighbors per iteration) ----------------
// lane = (q, fq): q = lane>>4 picks neighbor j+q, fq = lane&15 picks the feature slice.

// layer 1: bf16 xpad [N][64] (128B rows); fq owns cols 4fq..4fq+3 (uint2 8B)
__global__ __launch_bounds__(256) void aggregate50d_k(const unsigned short* __restrict__ xp,
                                                      const int* __restrict__ row_start,
                                                      const int* __restrict__ cnt,
                                                      const int* __restrict__ csr, int N,
                                                      unsigned short* __restrict__ aggp) {
    int wave = threadIdx.x >> 6;
    int lane = threadIdx.x & 63;
    int q  = lane >> 4;
    int fq = lane & 15;
    int i = blockIdx.x * 4 + wave;
    if (i >= N) return;
    int start = row_start[i];
    int deg = cnt[i];
    float a0 = 0.f, a1 = 0.f, a2 = 0.f, a3 = 0.f;
    for (int base = 0; base < deg; base += 64) {
        int nch = min(64, deg - base);
        int c = (base + lane < deg) ? csr[start + base + lane] : 0;
        int j = 0;
        for (; j + 4 <= nch; j += 4) {
            int cj = __shfl(c, j + q, 64);
            uint2 v = *reinterpret_cast<const uint2*>(xp + (size_t)cj * 64 + 4 * fq);
            a0 += b2f((unsigned short)(v.x & 0xffffu));
            a1 += b2f((unsigned short)(v.x >> 16));
            a2 += b2f((unsigned short)(v.y & 0xffffu));
            a3 += b2f((unsigned short)(v.y >> 16));
        }
        int rem = nch - j;
        if (rem > 0) {
            int cj = __shfl(c, min(j + q, 63), 64);  // all-lane shfl, clamp keeps src defined
            if (q < rem) {
                uint2 v = *reinterpret_cast<const uint2*>(xp + (size_t)cj * 64 + 4 * fq);
                a0 += b2f((unsigned short)(v.x & 0xffffu));
                a1 += b2f((unsigned short)(v.x >> 16));
                a2 += b2f((unsigned short)(v.y & 0xffffu));
                a3 += b2f((unsigned short)(v.y >> 16));
            }
        }
    }
    a0 += __shfl_xor(a0, 16, 64); a0 += __shfl_xor(a0, 32, 64);
    a1 += __shfl_xor(a1, 16, 64); a1 += __shfl_xor(a1, 32, 64);
    a2 += __shfl_xor(a2, 16, 64); a2 += __shfl_xor(a2, 32, 64);
    a3 += __shfl_xor(a3, 16, 64); a3 += __shfl_xor(a3, 32, 64);
    if (q == 0) {
        float inv = 1.f / fmaxf((float)deg, 1.f);
        uint2 o;
        o.x = (unsigned int)f2b(a0 * inv) | ((unsigned int)f2b(a1 * inv) << 16);
        o.y = (unsigned int)f2b(a2 * inv) | ((unsigned int)f2b(a3 * inv) << 16);
        *reinterpret_cast<uint2*>(aggp + (size_t)i * 64 + 4 * fq) = o;
    }
}

// layers 2/3: bf16 [N][128] (256B rows); fq owns cols 8fq..8fq+7 (uint4 16B)
__global__ __launch_bounds__(256) void aggregate128d_k(const unsigned short* __restrict__ x,
                                                       const int* __restrict__ row_start,
                                                       const int* __restrict__ cnt,
                                                       const int* __restrict__ csr, int N,
                                                       unsigned short* __restrict__ agg) {
    int wave = threadIdx.x >> 6;
    int lane = threadIdx.x & 63;
    int q  = lane >> 4;
    int fq = lane & 15;
    int i = blockIdx.x * 4 + wave;
    if (i >= N) return;
    int start = row_start[i];
    int deg = cnt[i];
    float a0=0.f,a1=0.f,a2=0.f,a3=0.f,a4=0.f,a5=0.f,a6=0.f,a7=0.f;
    for (int base = 0; base < deg; base += 64) {
        int nch = min(64, deg - base);
        int c = (base + lane < deg) ? csr[start + base + lane] : 0;
        int j = 0;
        for (; j + 4 <= nch; j += 4) {
            int cj = __shfl(c, j + q, 64);
            uint4 v = *reinterpret_cast<const uint4*>(x + (size_t)cj * 128 + 8 * fq);
            a0 += b2f((unsigned short)(v.x & 0xffffu)); a1 += b2f((unsigned short)(v.x >> 16));
            a2 += b2f((unsigned short)(v.y & 0xffffu)); a3 += b2f((unsigned short)(v.y >> 16));
            a4 += b2f((unsigned short)(v.z & 0xffffu)); a5 += b2f((unsigned short)(v.z >> 16));
            a6 += b2f((unsigned short)(v.w & 0xffffu)); a7 += b2f((unsigned short)(v.w >> 16));
        }
        int rem = nch - j;
        if (rem > 0) {
            int cj = __shfl(c, min(j + q, 63), 64);
            if (q < rem) {
                uint4 v = *reinterpret_cast<const uint4*>(x + (size_t)cj * 128 + 8 * fq);
                a0 += b2f((unsigned short)(v.x & 0xffffu)); a1 += b2f((unsigned short)(v.x >> 16));
                a2 += b2f((unsigned short)(v.y & 0xffffu)); a3 += b2f((unsigned short)(v.y >> 16));
                a4 += b2f((unsigned short)(v.z & 0xffffu)); a5 += b2f((unsigned short)(v.z >> 16));
                a6 += b2f((unsigned short)(v.w & 0xffffu)); a7 += b2f((unsigned short)(v.w >> 16));
            }
        }
    }
    a0 += __shfl_xor(a0, 16, 64); a0 += __shfl_xor(a0, 32, 64);
    a1 += __shfl_xor(a1, 16, 64); a1 += __shfl_xor(a1, 32, 64);
    a2 += __shfl_xor(a2, 16, 64); a2 += __shfl_xor(a2, 32, 64);
    a3 += __shfl_xor(a3, 16, 64); a3 += __shfl_xor(a3, 32, 64);
    a4 += __shfl_xor(a4, 16, 64); a4 += __shfl_xor(a4, 32, 64);
    a5 += __shfl_xor(a5, 16, 64); a5 += __shfl_xor(a5, 32, 64);
    a6 += __shfl_xor(a6, 16, 64); a6 += __shfl_xor(a6, 32, 64);
    a7 += __shfl_xor(a7, 16, 64); a7 += __shfl_xor(a7, 32, 64);
    if (q == 0) {
        float inv = 1.f / fmaxf((float)deg, 1.f);
        uint4 o;
        o.x = (unsigned int)f2b(a0 * inv) | ((unsigned int)f2b(a1 * inv) << 16);
        o.y = (unsigned int)f2b(a2 * inv) | ((unsigned int)f2b(a3 * inv) << 16);
        o.z = (unsigned int)f2b(a4 * inv) | ((unsigned int)f2b(a5 * inv) << 16);
        o.w = (unsigned int)f2b(a6 * inv) | ((unsigned int)f2b(a7 * inv) << 16);
        *reinterpret_cast<uint4*>(agg + (size_t)i * 128 + 8 * fq) = o;
    }
}

// ---------------- MFMA GEMM + fused l2norm/relu/BN epilogue ----------------
// out[N,128] = bn(relu(l2norm([A|B] @ W + bias))), A,B bf16 [N][KT*16], W via Wf.
// A-frag: lane l holds A[row=l&15][k=(l>>4)*8+j]. C-layout: col=lane&15, row=(lane>>4)*4+reg.

template <int KT>  // K = KT*32; halves A,B each KT*16 wide
__global__ __launch_bounds__(256) void gemm_mfma_k(
    const unsigned short* __restrict__ A, const unsigned short* __restrict__ B,
    const unsigned short* __restrict__ Wf, const float* __restrict__ bias,
    const float* __restrict__ gamma, const float* __restrict__ beta,
    const float* __restrict__ mean, const float* __restrict__ var,
    int N, unsigned short* __restrict__ out) {
    constexpr int S = KT * 16;
    const int tid = threadIdx.x;
    const int l   = tid & 63;
    const int w   = tid >> 6;
    const int lr  = l & 15;
    const int hk  = l >> 4;
    const int rowBase = blockIdx.x * 64 + w * 16;

    int arow = rowBase + lr;
    if (arow > N - 1) arow = N - 1;  // clamp: loads valid, stores guarded
    const unsigned short* pa = A + (size_t)arow * S + hk * 8;
    const unsigned short* pb = B + (size_t)arow * S + hk * 8;

    f32x4 acc[8] = {};

#pragma unroll
    for (int t = 0; t < KT; ++t) {
        const unsigned short* src = (t < KT / 2) ? (pa + t * 32) : (pb + (t - KT / 2) * 32);
        short8 af = *reinterpret_cast<const short8*>(src);
#pragma unroll
        for (int n = 0; n < 8; ++n) {
            short8 bf = *reinterpret_cast<const short8*>(Wf + ((size_t)(n * KT + t) * 64 + l) * 8);
            acc[n] = __builtin_amdgcn_mfma_f32_16x16x32_bf16(af, bf, acc[n], 0, 0, 0);
        }
    }

    float bs[8], mu[8], sc[8], bt[8];
#pragma unroll
    for (int n = 0; n < 8; ++n) {
        int col = n * 16 + lr;
        bs[n] = bias[col];
        mu[n] = mean[col];
        sc[n] = rsqrtf(var[col] + 1e-3f) * gamma[col];
        bt[n] = beta[col];
    }
#pragma unroll
    for (int i = 0; i < 4; ++i) {
        int gr = rowBase + hk * 4 + i;
        float a[8];
        float ss = 0.f;
#pragma unroll
        for (int n = 0; n < 8; ++n) { a[n] = acc[n][i] + bs[n]; ss += a[n] * a[n]; }
        ss += __shfl_xor(ss, 1, 64);
        ss += __shfl_xor(ss, 2, 64);
        ss += __shfl_xor(ss, 4, 64);
        ss += __shfl_xor(ss, 8, 64);
        float rs = rsqrtf(fmaxf(ss, 1e-12f));
        if (gr < N) {
#pragma unroll
            for (int n = 0; n < 8; ++n) {
                float v = fmaxf(a[n] * rs, 0.f);
                v = (v - mu[n]) * sc[n] + bt[n];
                out[(size_t)gr * 128 + n * 16 + lr] = f2b(v);
            }
        }
    }
}

// ---------------- segment (graph) pooling ----------------

__global__ __launch_bounds__(128) void pool_k(const unsigned short* __restrict__ h,
                                              const int* __restrict__ seg, int N,
                                              float* __restrict__ pool) {
    int tx = threadIdx.x;  // feature 0..127
    int r0 = blockIdx.x * 64;
    int rend = min(r0 + 64, N);
    if (r0 >= N) return;
    int cur = seg[r0];
    float sum = 0.f;
    for (int r = r0; r < rend; r++) {
        int s = seg[r];
        float v = b2f(h[(size_t)r * 128 + tx]);
        if (s != cur) {
            atomicAdd(&pool[cur * 128 + tx], sum);
            cur = s;
            sum = v;
        } else {
            sum += v;
        }
    }
    atomicAdd(&pool[cur * 128 + tx], sum);
}

// ---------------- dense head: 64 blocks, one graph each ----------------

__global__ __launch_bounds__(256) void head_k(const float* __restrict__ pool,
                                              const int* __restrict__ seg, int N,
                                              const float* __restrict__ dw1, const float* __restrict__ db1,
                                              const float* __restrict__ dw2, const float* __restrict__ db2,
                                              const float* __restrict__ dw3, const float* __restrict__ db3,
                                              float* __restrict__ out) {
    __shared__ float p[128];
    __shared__ float z1[256];
    __shared__ float z2[128];
    __shared__ float z3[16];
    __shared__ float cntS;
    int g = blockIdx.x;
    int t = threadIdx.x;
    if (t == 0) {
        int lo = 0, hi = N;
        while (lo < hi) { int mid = (lo + hi) >> 1; if (seg[mid] < g) lo = mid + 1; else hi = mid; }
        int lo2 = lo, hi2 = N;
        while (lo2 < hi2) { int mid = (lo2 + hi2) >> 1; if (seg[mid] < g + 1) lo2 = mid + 1; else hi2 = mid; }
        cntS = fmaxf((float)(lo2 - lo), 1.f);
    }
    __syncthreads();
    if (t < 128) p[t] = pool[g * 128 + t] / cntS;
    __syncthreads();
    {
        float acc = db1[t];
        for (int k = 0; k < 128; k++) acc += p[k] * dw1[k * D1 + t];
        z1[t] = fmaxf(acc, 0.f);
    }
    __syncthreads();
    if (t < 128) {
        float acc = db2[t];
        for (int k = 0; k < 256; k++) acc += z1[k] * dw2[k * D2 + t];
        z2[t] = fmaxf(acc, 0.f);
    }
    __syncthreads();
    if (t < NCLS) {
        float acc = db3[t];
        for (int k = 0; k < 128; k++) acc += z2[k] * dw3[k * NCLS + t];
        z3[t] = acc;
    }
    __syncthreads();
    if (t == 0) {
        float mx = -1e30f;
        for (int j = 0; j < NCLS; j++) mx = fmaxf(mx, z3[j]);
        float sum = 0.f;
        float e[NCLS];
        for (int j = 0; j < NCLS; j++) { e[j] = expf(z3[j] - mx); sum += e[j]; }
        for (int j = 0; j < NCLS; j++) out[g * NCLS + j] = e[j] / sum;
    }
}

// ---------------- launch ----------------

extern "C" void kernel_launch(void* const* d_in, const int* in_sizes, int n_in,
                              void* d_out, int out_size, void* d_ws, size_t ws_size,
                              hipStream_t stream) {
    const float* x    = (const float*)d_in[0];
    const int* erow   = (const int*)d_in[1];
    const int* ecol   = (const int*)d_in[2];
    const int* seg    = (const int*)d_in[3];
    const float* w1   = (const float*)d_in[4];
    const float* b1   = (const float*)d_in[5];
    const float* w2   = (const float*)d_in[6];
    const float* b2   = (const float*)d_in[7];
    const float* w3   = (const float*)d_in[8];
    const float* b3   = (const float*)d_in[9];
    const float* g1   = (const float*)d_in[10];
    const float* be1  = (const float*)d_in[11];
    const float* m1   = (const float*)d_in[12];
    const float* v1   = (const float*)d_in[13];
    const float* g2   = (const float*)d_in[14];
    const float* be2  = (const float*)d_in[15];
    const float* m2   = (const float*)d_in[16];
    const float* v2   = (const float*)d_in[17];
    const float* g3   = (const float*)d_in[18];
    const float* be3  = (const float*)d_in[19];
    const float* m3   = (const float*)d_in[20];
    const float* v3   = (const float*)d_in[21];
    const float* dw1  = (const float*)d_in[22];
    const float* db1  = (const float*)d_in[23];
    const float* dw2  = (const float*)d_in[24];
    const float* db2  = (const float*)d_in[25];
    const float* dw3  = (const float*)d_in[26];
    const float* db3  = (const float*)d_in[27];
    float* out = (float*)d_out;

    const int N = in_sizes[3];
    const int E = in_sizes[1];

    char* ws = (char*)d_ws;
    size_t off = 0;
    auto alloc = [&](size_t bytes) -> char* {
        off = (off + 255) & ~(size_t)255;
        char* p = ws + off;
        off += bytes;
        return p;
    };
    int* cnt        = (int*)alloc((size_t)N * 4);
    int* row_start  = (int*)alloc((size_t)N * 4);
    int* partial    = (int*)alloc(1024 * 4);
    int* csr        = (int*)alloc((size_t)E * 4);
    int* eslot      = (int*)alloc((size_t)E * 4);
    unsigned short* xpad = (unsigned short*)alloc((size_t)N * 64 * 2);
    unsigned short* aggp = (unsigned short*)alloc((size_t)N * 64 * 2);
    unsigned short* hA   = (unsigned short*)alloc((size_t)N * 128 * 2);
    unsigned short* hB   = (unsigned short*)alloc((size_t)N * 128 * 2);
    unsigned short* aggb = (unsigned short*)alloc((size_t)N * 128 * 2);
    unsigned short* wf1 = (unsigned short*)alloc(128 * 128 * 2);
    unsigned short* wf2 = (unsigned short*)alloc(256 * 128 * 2);
    unsigned short* wf3 = (unsigned short*)alloc(256 * 128 * 2);
    float* pool     = (float*)alloc((size_t)NG * 128 * 4);

    hipMemsetAsync(cnt, 0, (size_t)N * 4, stream);
    hipMemsetAsync(pool, 0, (size_t)NG * 128 * 4, stream);

    const int nbScan = (N + 1023) / 1024;
    count_edges_k<<<(E + 255) / 256, 256, 0, stream>>>(erow, E, cnt, eslot);
    scan_partial_k<<<nbScan, 256, 0, stream>>>(cnt, N, partial);
    scan_partials_serial_k<<<1, 64, 0, stream>>>(partial, nbScan);
    scan_final_k<<<nbScan, 1024, 0, stream>>>(cnt, N, partial, row_start);
    const int half = N / 2;
    fill_csr2_k<<<(E + 255) / 256, 256, 0, stream>>>(erow, ecol, eslot, E, row_start, csr, 0, half);
    fill_csr2_k<<<(E + 255) / 256, 256, 0, stream>>>(erow, ecol, eslot, E, row_start, csr, half, N);

    // weight prep + x pad
    wf1p_k<<<(4 * 4096) / 256, 256, 0, stream>>>(w1, wf1);
    wf_k<<<(8 * 4096) / 256, 256, 0, stream>>>(w2, 8, wf2);
    wf_k<<<(8 * 4096) / 256, 256, 0, stream>>>(w3, 8, wf3);
    copyx_k<<<(N * 32 + 255) / 256, 256, 0, stream>>>(x, xpad, N);

    const int aggGrid = (N + 3) / 4;
    const int gemmGrid = (N + 63) / 64;

    // layer 1 (K=128 padded)
    aggregate50d_k<<<aggGrid, 256, 0, stream>>>(xpad, row_start, cnt, csr, N, aggp);
    gemm_mfma_k<4><<<gemmGrid, 256, 0, stream>>>(xpad, aggp, wf1, b1, g1, be1, m1, v1, N, hA);
    // layer 2 (K=256)
    aggregate128d_k<<<aggGrid, 256, 0, stream>>>(hA, row_start, cnt, csr, N, aggb);
    gemm_mfma_k<8><<<gemmGrid, 256, 0, stream>>>(hA, aggb, wf2, b2, g2, be2, m2, v2, N, hB);
    // layer 3 (K=256)
    aggregate128d_k<<<aggGrid, 256, 0, stream>>>(hB, row_start, cnt, csr, N, aggb);
    gemm_mfma_k<8><<<gemmGrid, 256, 0, stream>>>(hB, aggb, wf3, b3, g3, be3, m3, v3, N, hA);

    // pooling + head
    pool_k<<<(N + 63) / 64, 128, 0, stream>>>(hA, seg, N, pool);
    head_k<<<NG, 256, 0, stream>>>(pool, seg, N, dw1, db1, dw2, db2, dw3, db3, out);
}